// Round 11
// baseline (16711.624 us; speedup 1.0000x reference)
//
#include <hip/hip_runtime.h>
#include <math.h>

// ---------------- config ----------------
#define TF_PARTITIONABLE 1   // jax threefry_partitionable (default True since jax 0.4.36)

static constexpr int Bn=64, Ln=512, En=512, Tn=512, Sn=512, Pn=256, An=1024, Dn=1024, Gn=128, Vn=148;
static constexpr int G4A = 4096;            // 4*A == 4*D
static constexpr int KPROJ = Dn + En;       // 1536
static constexpr int KATT = 1792, KDEC = 2560;
static constexpr int ACH = 8, ACK = 224;    // att gates K = 8 chunks x 224 (1 stage each)
static constexpr int DCH = 8, DCK = 320;    // dec gates K = 8 chunks x 320
static constexpr int NKB_ATT = KATT / 32;   // 56 k-blocks
static constexpr int NKB_DEC = KDEC / 32;   // 80
static constexpr long LOGITS_OFF = 0;
static constexpr long ALIGNS_OFF = (long)Bn*Tn*Vn;               // 4,849,664
static constexpr long PARAMS_OFF = ALIGNS_OFF + (long)Bn*Tn*Ln;  // 21,626,880

using s16x8 = __attribute__((ext_vector_type(8))) short;
using f32x4 = __attribute__((ext_vector_type(4))) float;

// ---------------- threefry2x32 (jax-exact) ----------------
struct TFo { unsigned a, b; };
static constexpr TFo htf(unsigned k1, unsigned k2, unsigned x0, unsigned x1) {
  unsigned ks2 = k1 ^ k2 ^ 0x1BD11BDAu;
  unsigned ks[3] = {k1, k2, ks2};
  const unsigned ra[4] = {13u,15u,26u,6u}, rb[4] = {17u,29u,16u,24u};
  x0 += k1; x1 += k2;
  for (int g = 0; g < 5; ++g) {
    const unsigned* r = (g % 2 == 0) ? ra : rb;
    for (int i = 0; i < 4; ++i) { x0 += x1; x1 = (x1 << r[i]) | (x1 >> (32u - r[i])); x1 ^= x0; }
    x0 += ks[(g+1)%3]; x1 += ks[(g+2)%3] + (unsigned)(g+1);
  }
  return TFo{x0, x1};
}
#if TF_PARTITIONABLE
static constexpr TFo DK1 = htf(0u,42u,0u,0u);
static constexpr TFo DK2 = htf(0u,42u,0u,1u);
#else
static constexpr TFo S02 = htf(0u,42u,0u,2u);
static constexpr TFo S13 = htf(0u,42u,1u,3u);
static constexpr TFo DK1 = TFo{S02.a, S13.a};
static constexpr TFo DK2 = TFo{S02.b, S13.b};
#endif

__device__ __forceinline__ void dtf(unsigned k1, unsigned k2, unsigned x0, unsigned x1,
                                    unsigned& o0, unsigned& o1) {
  unsigned ks2 = k1 ^ k2 ^ 0x1BD11BDAu;
#define TFR(r) { x0 += x1; x1 = (x1<<r)|(x1>>(32-r)); x1 ^= x0; }
  x0 += k1; x1 += k2;
  TFR(13) TFR(15) TFR(26) TFR(6)  x0 += k2;  x1 += ks2 + 1u;
  TFR(17) TFR(29) TFR(16) TFR(24) x0 += ks2; x1 += k1 + 2u;
  TFR(13) TFR(15) TFR(26) TFR(6)  x0 += k1;  x1 += k2 + 3u;
  TFR(17) TFR(29) TFR(16) TFR(24) x0 += k2;  x1 += ks2 + 4u;
  TFR(13) TFR(15) TFR(26) TFR(6)  x0 += ks2; x1 += k1 + 5u;
#undef TFR
  o0 = x0; o1 = x1;
}

__device__ __forceinline__ bool keepmask(unsigned ka, unsigned kb, unsigned j) {
#if TF_PARTITIONABLE
  unsigned o0, o1; dtf(ka, kb, 0u, j, o0, o1);
  return ((o0 ^ o1) >> 31) == 0u;
#else
  const unsigned H = 4202496u;  // (513*64*256)/2
  unsigned o0, o1;
  if (j < H) { dtf(ka, kb, j, j + H, o0, o1); return (o0 >> 31) == 0u; }
  else       { dtf(ka, kb, j - H, j, o0, o1); return (o1 >> 31) == 0u; }
#endif
}

// ---------------- dtype helpers ----------------
__device__ __forceinline__ float ldbf(const unsigned short* p, long i) {
  return __uint_as_float(((unsigned)p[i]) << 16);
}
__device__ __forceinline__ float bflo(unsigned q) { return __uint_as_float(q << 16); }
__device__ __forceinline__ float bfhi(unsigned q) { return __uint_as_float(q & 0xffff0000u); }
__device__ __forceinline__ unsigned short f2bf(float v) {
  unsigned x = __float_as_uint(v);
  return (unsigned short)((x + 0x7fffu + ((x >> 16) & 1u)) >> 16);  // RNE
}
__device__ __forceinline__ void store_out(void* out, long i, float v, int bf) {
  if (bf) ((unsigned short*)out)[i] = f2bf(v);
  else    ((float*)out)[i] = v;
}
__device__ __forceinline__ float st_load(const float* p, long i) { return p[i]; }
__device__ __forceinline__ float st_load(const unsigned short* p, long i) { return ldbf(p, i); }
__device__ __forceinline__ void st_store(float* p, long i, float v) { p[i] = v; }
__device__ __forceinline__ void st_store(unsigned short* p, long i, float v) { p[i] = f2bf(v); }
__device__ __forceinline__ float sigm(float x) { return 1.f / (1.f + expf(-x)); }
__device__ __forceinline__ void st4bf(unsigned short* p, float a, float b, float c, float d) {
  union { unsigned short u[4]; uint2 v; } q;
  q.u[0] = f2bf(a); q.u[1] = f2bf(b); q.u[2] = f2bf(c); q.u[3] = f2bf(d);
  *(uint2*)p = q.v;
}
__device__ __forceinline__ void st8bf(unsigned short* p, const float* h) {
  union { unsigned short u[8]; uint4 v; } q;
#pragma unroll
  for (int i = 0; i < 8; ++i) q.u[i] = f2bf(h[i]);
  *(uint4*)p = q.v;
}

// ---------------- pointer pack ----------------
struct Ptrs {
  const float *Wp1,*Wp2,*bai,*bah,*Wg1,*bg1,*Wg2,*bdi,*bdh,*Wpr,*bpr;
  unsigned short *PWatt,*PWdec,*pre_bf,*attA,*decA;
  float *Patt,*Pdec,*ac,*dc,*mean;
  void *dh_all,*ctx_all;
  const void *mem,*din,*w_ai,*w_ah,*w_di,*w_dh;
  const int *mlen; const int *flag; void *out;
};

// ---------------- utility kernels ----------------
__global__ __launch_bounds__(256) void k_detect(const void* mem, int* flag) {
  __shared__ int cnt;
  int tid = threadIdx.x;
  if (tid == 0) cnt = 0;
  __syncthreads();
  const unsigned short* p = (const unsigned short*)mem;
  int local = 0;
  for (int i = tid; i < 1024; i += 256) {
    float f = ldbf(p, 2L * i);
    if (f == f && fabsf(f) > 0.0009f && fabsf(f) < 16.f) local++;
  }
  atomicAdd(&cnt, local);
  __syncthreads();
  if (tid == 0) flag[0] = (cnt > 512) ? 1 : 0;
}

__global__ __launch_bounds__(256) void k_convert(const void* src, float* dst, long n, const int* flag) {
  int bf = *flag;
  long i0 = (long)blockIdx.x * 256 + threadIdx.x, stp = (long)gridDim.x * 256;
  if (bf) { const unsigned short* s = (const unsigned short*)src;
            for (long i = i0; i < n; i += stp) dst[i] = ldbf(s, i); }
  else    { const float* s = (const float*)src;
            for (long i = i0; i < n; i += stp) dst[i] = s[i]; }
}

__global__ __launch_bounds__(256) void k_zero_f32(float* p, long n) {
  for (long i = (long)blockIdx.x * 256 + threadIdx.x; i < n; i += (long)gridDim.x * 256) p[i] = 0.f;
}

__global__ __launch_bounds__(256) void k_zero_aligns(void* out, const int* flag) {
  int bf = *flag;
  unsigned* p; long n;
  if (bf) { p = (unsigned*)out + (ALIGNS_OFF >> 1); n = ((long)Bn*Tn*Ln) >> 1; }
  else    { p = (unsigned*)out + ALIGNS_OFF;        n = (long)Bn*Tn*Ln; }
  for (long i = (long)blockIdx.x * 256 + threadIdx.x; i < n; i += (long)gridDim.x * 256) p[i] = 0u;
}

// copy pre(0) into attA pre segment (prologue only)
__global__ __launch_bounds__(256) void k_precopy(Ptrs P) {
  int tid = threadIdx.x;
  for (int i = tid; i < 2048; i += 256) {
    int b = i >> 5, g = i & 31;
    *(uint4*)(P.attA + (long)b * KATT + g * 8) =
        *(const uint4*)(P.pre_bf + (long)b * Pn + g * 8);
  }
}

// ---------------- weight packing: bf16 B-fragment order ----------------
// PW[kblk][nblk][lane][8]: lane l elem j <-> W[kblk*32 + (l>>4)*8 + j][nblk*16 + (l&15)]
__global__ __launch_bounds__(256) void k_pack(Ptrs P) {
  __shared__ float s[32][65];
  int bid = blockIdx.x, tid = threadIdx.x;
  bool att = bid < NKB_ATT * 64;
  int lb = att ? bid : bid - NKB_ATT * 64;
  int kblk = lb >> 6, ng = lb & 63;
  int n0 = ng * 64;
  int bf = *P.flag;
  int split = att ? (Pn + En) : (An + En);
  const void* S0 = att ? P.w_ai : P.w_di;
  const void* S1 = att ? P.w_ah : P.w_dh;
  for (int i = tid; i < 2048; i += 256) {
    int kk = i >> 6, n = i & 63;
    int k = kblk * 32 + kk;
    const void* src = (k < split) ? S0 : S1;
    long idx = (long)(k < split ? k : k - split) * G4A + (n0 + n);
    s[kk][n] = bf ? ldbf((const unsigned short*)src, idx) : ((const float*)src)[idx];
  }
  __syncthreads();
  int lane = tid & 63, tb = tid >> 6;
  unsigned short r[8];
#pragma unroll
  for (int j = 0; j < 8; ++j)
    r[j] = f2bf(s[(lane >> 4) * 8 + j][tb * 16 + (lane & 15)]);
  unsigned short* out = (att ? P.PWatt : P.PWdec) +
      (((long)kblk * 256 + (ng * 4 + tb)) * 64 + lane) * 8;
  *(uint4*)out = *(const uint4*)r;
}

// ---------------- prenet (fused GEMM1+mask1+GEMM2+mask2) -> bf16 ----------------
__global__ __launch_bounds__(256) void k_prenet(Ptrs P, unsigned k1a, unsigned k1b,
                                                unsigned k2a, unsigned k2b) {
  __shared__ __align__(16) float x_s[32 * 17];
  __shared__ __align__(16) float W_s[16 * 256];
  __shared__ __align__(16) float h1_s[32 * 258];
  int bid = blockIdx.x, tid = threadIdx.x;
  int t = bid >> 1, half = bid & 1;
  int bf = *P.flag;
  int tc = tid & 63, tr = tid >> 6;
  int p0 = tc * 4, bl0 = tr * 8;
  float acc[8][4];
#pragma unroll
  for (int i = 0; i < 8; ++i) { acc[i][0]=0; acc[i][1]=0; acc[i][2]=0; acc[i][3]=0; }

  for (int kc = 0; kc < 32; ++kc) {
    __syncthreads();
    for (int i = tid; i < 32 * 16; i += 256) {
      int bl = i >> 4, kk = i & 15;
      int s = kc * 16 + kk;
      float v = 0.f;
      if (t > 0) {
        long idx = ((long)(half * 32 + bl) * Sn + s) * Tn + (t - 1);
        v = bf ? ldbf((const unsigned short*)P.din, idx) : ((const float*)P.din)[idx];
      }
      x_s[bl * 17 + kk] = v;
    }
    for (int i = tid; i < 16 * 256; i += 256) {
      int kk = i >> 8, p = i & 255;
      W_s[kk * 256 + p] = P.Wp1[(long)(kc * 16 + kk) * 256 + p];
    }
    __syncthreads();
    for (int kk = 0; kk < 16; ++kk) {
      float4 w = *(const float4*)(W_s + kk * 256 + p0);
#pragma unroll
      for (int i = 0; i < 8; ++i) {
        float x = x_s[(bl0 + i) * 17 + kk];
        acc[i][0] += x * w.x; acc[i][1] += x * w.y; acc[i][2] += x * w.z; acc[i][3] += x * w.w;
      }
    }
  }
#pragma unroll
  for (int i = 0; i < 8; ++i)
#pragma unroll
    for (int j = 0; j < 4; ++j) {
      int bl = bl0 + i, p = p0 + j, bg = half * 32 + bl;
      float v = fmaxf(acc[i][j], 0.f);
      unsigned ft = (unsigned)(((long)t * 64 + bg) * 256 + p);
      v = keepmask(k1a, k1b, ft) ? 2.f * v : 0.f;
      h1_s[bl * 258 + p] = v;
      acc[i][j] = 0.f;
    }
  __syncthreads();
  for (int kc = 0; kc < 16; ++kc) {
    __syncthreads();
    for (int i = tid; i < 16 * 256; i += 256) {
      int kk = i >> 8, p = i & 255;
      W_s[kk * 256 + p] = P.Wp2[(long)(kc * 16 + kk) * 256 + p];
    }
    __syncthreads();
    for (int kk = 0; kk < 16; ++kk) {
      float4 w = *(const float4*)(W_s + kk * 256 + p0);
      int s = kc * 16 + kk;
#pragma unroll
      for (int i = 0; i < 8; ++i) {
        float x = h1_s[(bl0 + i) * 258 + s];
        acc[i][0] += x * w.x; acc[i][1] += x * w.y; acc[i][2] += x * w.z; acc[i][3] += x * w.w;
      }
    }
  }
#pragma unroll
  for (int i = 0; i < 8; ++i)
#pragma unroll
    for (int j = 0; j < 4; ++j) {
      int bg = half * 32 + bl0 + i, p = p0 + j;
      float v = fmaxf(acc[i][j], 0.f);
      unsigned ft = (unsigned)(((long)t * 64 + bg) * 256 + p);
      v = keepmask(k2a, k2b, ft) ? 2.f * v : 0.f;
      P.pre_bf[((long)t * 64 + bg) * 256 + p] = f2bf(v);
    }
}

// ---------------- K1: MFMA gate GEMMs, 8 K-chunks, single-stage LDS A ----------------
// 1024 blocks x 256 thr: bid<512 att gates(t+1) [cg=bid>>3, kc=bid&7],
//                        else   dec gates(t)   [cg=(bid-512)>>3, kc=bid&7].
// bid&7 = kc => with round-robin block->XCD dispatch, each XCD re-reads the same
// (att 1.8 MB + dec 2.6 MB) weight K-slice every step.
template<bool ATT>
__device__ __forceinline__ void dev_gemm(const Ptrs& P, int cg, int kc, unsigned short* a_lds) {
  constexpr int CK    = ATT ? ACK : DCK;      // 224 / 320 (single stage)
  constexpr int NKS   = CK / 32;              // 7 / 10
  constexpr int PITCH = CK + 8;               // <=2-way LDS bank aliasing (free)
  constexpr int GPR   = CK / 8;               // 16B groups per row: 28 / 40
  constexpr int KSTR  = ATT ? KATT : KDEC;    // A row stride (contiguous packed)
  int tid = threadIdx.x;
  int lane = tid & 63, w = tid >> 6;
  int nblk = cg * 4 + w;
  const unsigned short* PW = ATT ? P.PWatt : P.PWdec;
  const unsigned short* A  = ATT ? P.attA : P.decA;
  int rlo = lane & 15, khi8 = (lane >> 4) * 8;
  const int k0 = kc * CK;

  f32x4 acc[4];
#pragma unroll
  for (int i = 0; i < 4; ++i) acc[i] = f32x4{0.f, 0.f, 0.f, 0.f};

#pragma unroll
  for (int i = 0; i < GPR / 4; ++i) {         // branch-free coalesced staging
    int g = tid + i * 256;
    int row = g / GPR, kg = (g - row * GPR) * 8;
    *(uint4*)(a_lds + row * PITCH + kg) = *(const uint4*)(A + (long)row * KSTR + k0 + kg);
  }
  __syncthreads();
  const unsigned short* bptr = PW + (((long)(k0 >> 5) * 256 + nblk) * 64 + lane) * 8;
  s16x8 br[4];
#pragma unroll
  for (int i = 0; i < 4; ++i) br[i] = *(const s16x8*)(bptr + (long)i * 131072);
#pragma unroll
  for (int kb = 0; kb < NKS; ++kb) {
    s16x8 bcur = br[kb & 3];
    if (kb + 4 < NKS) br[kb & 3] = *(const s16x8*)(bptr + (long)(kb + 4) * 131072);
    int abase = kb * 32 + khi8;
#pragma unroll
    for (int mb = 0; mb < 4; ++mb) {
      s16x8 a = *(const s16x8*)(a_lds + (mb * 16 + rlo) * PITCH + abase);
      acc[mb] = __builtin_amdgcn_mfma_f32_16x16x32_bf16(a, bcur, acc[mb], 0, 0, 0);
    }
  }
  float* Pout = (ATT ? P.Patt : P.Pdec) + (long)kc * 64 * G4A;
  int col = nblk * 16 + rlo, rbase = (lane >> 4) * 4;
#pragma unroll
  for (int mb = 0; mb < 4; ++mb)
#pragma unroll
    for (int r = 0; r < 4; ++r)
      Pout[(long)(mb * 16 + rbase + r) * G4A + col] = acc[mb][r];
}

__global__ __launch_bounds__(256) void k_gemm(Ptrs P, int t) {
  __shared__ __align__(16) unsigned short a_lds[64 * 328];  // dec pitch (42 KB) -> 3 blocks/CU
  int bid = blockIdx.x;
  int kc = bid & 7;
  bool att = bid < 512;
  int cg = (att ? bid : bid - 512) >> 3;
  if (att) { if (t + 1 < Tn) dev_gemm<true>(P, cg, kc, a_lds); }
  else     { if (t >= 0 && t < Tn) dev_gemm<false>(P, cg, kc, a_lds); }
}

// ---------------- K2: pointwise phase (96 blocks x 256) ----------------
// blocks 0..63: att LSTM pw(t)+GMM+alpha+ctx.  blocks 64..95: dec LSTM pw(t-1).
template<typename ST>
__global__ __launch_bounds__(256) void k_point(Ptrs P, int t) {
  __shared__ float ah_s[1024];
  __shared__ float red_s[256];
  __shared__ float tanh_s[128];
  __shared__ float bc_s[2];
  __shared__ float alpha_s[176];
  int bid = blockIdx.x, tid = threadIdx.x;
  if (bid < 64) {
    if (t >= Tn) return;
    int b = bid;
    int bf = *P.flag;
    // copy pre(t+1) into attA pre segment (for next k_gemm)
    if (t + 1 < Tn && tid < 32) {
      *(uint4*)(P.attA + (long)b * KATT + tid * 8) =
          *(const uint4*)(P.pre_bf + ((long)(t + 1) * 64 + b) * Pn + tid * 8);
    }
    int u0 = tid * 4;
    float gv[4][4];
#pragma unroll
    for (int gt = 0; gt < 4; ++gt) {
      float4 a = *(const float4*)(P.bai + gt * 1024 + u0);
      float4 c = *(const float4*)(P.bah + gt * 1024 + u0);
      gv[gt][0] = a.x + c.x; gv[gt][1] = a.y + c.y; gv[gt][2] = a.z + c.z; gv[gt][3] = a.w + c.w;
    }
#pragma unroll
    for (int kc = 0; kc < ACH; ++kc) {
      const float* pa = P.Patt + ((long)kc * 64 + b) * G4A + u0;
#pragma unroll
      for (int gt = 0; gt < 4; ++gt) {
        float4 v = *(const float4*)(pa + gt * 1024);
        gv[gt][0] += v.x; gv[gt][1] += v.y; gv[gt][2] += v.z; gv[gt][3] += v.w;
      }
    }
    float4 oc = *(const float4*)(P.ac + b * 1024 + u0);
    float oldc[4] = {oc.x, oc.y, oc.z, oc.w};
    float hh[4], cc[4];
#pragma unroll
    for (int i = 0; i < 4; ++i) {
      float ii = sigm(gv[0][i]), ff = sigm(gv[1][i]), oo = sigm(gv[3][i]);
      cc[i] = ff * oldc[i] + ii * tanhf(gv[2][i]);
      hh[i] = oo * tanhf(cc[i]);
      ah_s[u0 + i] = hh[i];
    }
    *(float4*)(P.ac + b * 1024 + u0) = make_float4(cc[0], cc[1], cc[2], cc[3]);
    st4bf(P.attA + (long)b * KATT + 768 + u0, hh[0], hh[1], hh[2], hh[3]);
    st4bf(P.decA + (long)b * KDEC + u0,       hh[0], hh[1], hh[2], hh[3]);
    __syncthreads();
    // GMM hidden: tanh(ah @ W_g1 + b_g1)
    {
      int g = tid & 127, hf = tid >> 7;
      const float* wg = P.Wg1 + g;
      float a0 = 0.f, a1 = 0.f;
      int ub = hf * 512;
      for (int u = ub; u < ub + 512; u += 2) {
        a0 += ah_s[u]     * wg[(long)u * 128];
        a1 += ah_s[u + 1] * wg[(long)(u + 1) * 128];
      }
      red_s[tid] = a0 + a1;
    }
    __syncthreads();
    if (tid < 128) tanh_s[tid] = tanhf(red_s[tid] + red_s[tid + 128] + P.bg1[tid]);
    __syncthreads();
    if (tid < 64) {
      float tv0 = tanh_s[tid], tv1 = tanh_s[tid + 64];
      float h0 = tv0 * P.Wg2[2 * tid]     + tv1 * P.Wg2[2 * (tid + 64)];
      float h1 = tv0 * P.Wg2[2 * tid + 1] + tv1 * P.Wg2[2 * (tid + 64) + 1];
#pragma unroll
      for (int o = 32; o; o >>= 1) { h0 += __shfl_down(h0, o); h1 += __shfl_down(h1, o); }
      if (tid == 0) {
        float m  = P.mean[b] + expf(h0) * 8.f;
        float sc = expf(h1) * 8.f;
        P.mean[b] = m;
        long pidx = PARAMS_OFF + ((long)b * Tn + t) * 2;
        store_out(P.out, pidx, h0, bf);
        store_out(P.out, pidx + 1, h1, bf);
        bc_s[0] = m; bc_s[1] = sc;
      }
    }
    __syncthreads();
    float m = bc_s[0], sc = bc_s[1];
    int len = P.mlen[b];
    int ci = (int)floorf(fminf(m, 100000.f));
    int l0 = ci - 80; if (l0 < 0) l0 = 0;
    int l1 = ci + 81; if (l1 > len) l1 = len;
    float inv2 = 0.5f / (sc * sc);
    float invZ = 1.f / (2.50662827463100050242f * sc);
    for (int l = l0 + tid; l < l1; l += 256) {
      float d = (float)l - m;
      float al = expf(-d * d * inv2) * invZ;
      alpha_s[l - l0] = al;
      store_out(P.out, ALIGNS_OFF + ((long)b * Tn + t) * Ln + l, al, bf);
    }
    __syncthreads();
    int nl = l1 - l0;
    ST* ctx_all = (ST*)P.ctx_all;
    int e0 = tid * 2;
    float s0 = 0.f, s1 = 0.f;
    if (bf) {
      const unsigned* mem = (const unsigned*)((const unsigned short*)P.mem +
                                              ((long)b * Ln + l0) * En + e0);
      for (int l = 0; l < nl; ++l) {
        float al = alpha_s[l];
        unsigned q = mem[(long)l * (En / 2)];
        s0 += al * bflo(q);
        s1 += al * bfhi(q);
      }
    } else {
      const float* mem = (const float*)P.mem + ((long)b * Ln + l0) * En + e0;
      for (int l = 0; l < nl; ++l) {
        float al = alpha_s[l];
        float2 v = *(const float2*)(mem + (long)l * En);
        s0 += al * v.x;
        s1 += al * v.y;
      }
    }
    unsigned q = (unsigned)f2bf(s0) | ((unsigned)f2bf(s1) << 16);
    *(unsigned*)(P.attA + (long)b * KATT + 256 + e0) = q;
    *(unsigned*)(P.decA + (long)b * KDEC + 1024 + e0) = q;
    st_store(ctx_all, ((long)t * 64 + b) * En + e0, s0);
    st_store(ctx_all, ((long)t * 64 + b) * En + e0 + 1, s1);
  } else {
    if (t == 0) return;
    int bb = bid - 64;
    int b = bb * 2 + (tid >> 7);
    int u0 = (tid & 127) * 8;
    ST* dh_all = (ST*)P.dh_all;
    float gv[4][8];
#pragma unroll
    for (int gt = 0; gt < 4; ++gt) {
      float4 a0 = *(const float4*)(P.bdi + gt * 1024 + u0);
      float4 a1 = *(const float4*)(P.bdi + gt * 1024 + u0 + 4);
      float4 c0 = *(const float4*)(P.bdh + gt * 1024 + u0);
      float4 c1 = *(const float4*)(P.bdh + gt * 1024 + u0 + 4);
      gv[gt][0] = a0.x + c0.x; gv[gt][1] = a0.y + c0.y; gv[gt][2] = a0.z + c0.z; gv[gt][3] = a0.w + c0.w;
      gv[gt][4] = a1.x + c1.x; gv[gt][5] = a1.y + c1.y; gv[gt][6] = a1.z + c1.z; gv[gt][7] = a1.w + c1.w;
    }
#pragma unroll
    for (int kc = 0; kc < DCH; ++kc) {
      const float* pd = P.Pdec + ((long)kc * 64 + b) * G4A + u0;
#pragma unroll
      for (int gt = 0; gt < 4; ++gt) {
        float4 v0 = *(const float4*)(pd + gt * 1024);
        float4 v1 = *(const float4*)(pd + gt * 1024 + 4);
        gv[gt][0] += v0.x; gv[gt][1] += v0.y; gv[gt][2] += v0.z; gv[gt][3] += v0.w;
        gv[gt][4] += v1.x; gv[gt][5] += v1.y; gv[gt][6] += v1.z; gv[gt][7] += v1.w;
      }
    }
    float4 oc0 = *(const float4*)(P.dc + b * 1024 + u0);
    float4 oc1 = *(const float4*)(P.dc + b * 1024 + u0 + 4);
    float oldc[8] = {oc0.x, oc0.y, oc0.z, oc0.w, oc1.x, oc1.y, oc1.z, oc1.w};
    float hh[8], cc[8];
#pragma unroll
    for (int i = 0; i < 8; ++i) {
      float ii = sigm(gv[0][i]), ff = sigm(gv[1][i]), oo = sigm(gv[3][i]);
      cc[i] = ff * oldc[i] + ii * tanhf(gv[2][i]);
      hh[i] = oo * tanhf(cc[i]);
    }
    *(float4*)(P.dc + b * 1024 + u0)     = make_float4(cc[0], cc[1], cc[2], cc[3]);
    *(float4*)(P.dc + b * 1024 + u0 + 4) = make_float4(cc[4], cc[5], cc[6], cc[7]);
    st8bf(P.decA + (long)b * KDEC + 1536 + u0, hh);
#pragma unroll
    for (int i = 0; i < 8; ++i)
      st_store(dh_all, ((long)(t - 1) * 64 + b) * 1024 + u0 + i, hh[i]);
  }
}

// ---------------- final projection: logits = [dh, ctx] @ W_proj + b ----------------
template<typename ST>
__global__ __launch_bounds__(256) void k_proj(Ptrs P) {
  __shared__ __align__(16) float A_s[64][65];
  __shared__ __align__(16) float W_s[64 * 160];
  int t = blockIdx.x, tid = threadIdx.x;
  int bf = *P.flag;
  const ST* dh_all = (const ST*)P.dh_all;
  const ST* ctx_all = (const ST*)P.ctx_all;
  int tc = tid & 15, tr = tid >> 4;
  int c0 = tc * 10, b0 = tr * 4;
  float acc[4][10];
#pragma unroll
  for (int i = 0; i < 4; ++i)
#pragma unroll
    for (int j = 0; j < 10; ++j) acc[i][j] = 0.f;
  for (int k0 = 0; k0 < KPROJ; k0 += 64) {
    __syncthreads();
    for (int i = tid; i < 64 * 64; i += 256) {
      int b = i >> 6, kk = i & 63;
      int k = k0 + kk;
      float v = (k < Dn) ? st_load(dh_all, ((long)t * 64 + b) * Dn + k)
                         : st_load(ctx_all, ((long)t * 64 + b) * En + (k - Dn));
      A_s[b][kk] = v;
    }
    for (int i = tid; i < 64 * 160; i += 256) {
      int kk = i / 160, c = i - kk * 160;
      W_s[kk * 160 + c] = (c < Vn) ? P.Wpr[(long)(k0 + kk) * Vn + c] : 0.f;
    }
    __syncthreads();
    for (int kk = 0; kk < 64; ++kk) {
      float xs[4];
#pragma unroll
      for (int i = 0; i < 4; ++i) xs[i] = A_s[b0 + i][kk];
#pragma unroll
      for (int j = 0; j < 10; ++j) {
        float w = W_s[kk * 160 + c0 + j];
#pragma unroll
        for (int i = 0; i < 4; ++i) acc[i][j] += xs[i] * w;
      }
    }
  }
#pragma unroll
  for (int i = 0; i < 4; ++i)
#pragma unroll
    for (int j = 0; j < 10; ++j) {
      int c = c0 + j;
      if (c < Vn) {
        int b = b0 + i;
        store_out(P.out, LOGITS_OFF + ((long)b * Tn + t) * Vn + c, acc[i][j] + P.bpr[c], bf);
      }
    }
}

// ---------------- host ----------------
template<typename ST>
static void run_pipeline(const Ptrs& P, hipStream_t stream) {
  k_prenet<<<Tn * 2, 256, 0, stream>>>(P, DK1.a, DK1.b, DK2.a, DK2.b);
  k_precopy<<<1, 256, 0, stream>>>(P);                  // pre(0) -> attA
  k_gemm<<<1024, 256, 0, stream>>>(P, -1);              // prologue: att gates for t=0
  for (int t = 0; t <= Tn; ++t) {
    k_point<ST><<<96, 256, 0, stream>>>(P, t);          // att pw(t)+GMM+ctx | dec pw(t-1)
    if (t < Tn) k_gemm<<<1024, 256, 0, stream>>>(P, t); // att gates(t+1) + dec gates(t)
  }
  k_proj<ST><<<Tn, 256, 0, stream>>>(P);
}

extern "C" void kernel_launch(void* const* d_in, const int* in_sizes, int n_in,
                              void* d_out, int out_size, void* d_ws, size_t ws_size,
                              hipStream_t stream) {
  (void)in_sizes; (void)n_in; (void)out_size;
  char* base = (char*)d_ws;
  int* flag = (int*)base;
  size_t off = 256;
  auto allocf = [&](size_t n) -> float* {
    float* p = (float*)(base + off);
    off += ((n * 4 + 255) / 256) * 256;
    return p;
  };
  auto allocu = [&](size_t n) -> unsigned short* {
    unsigned short* p = (unsigned short*)(base + off);
    off += ((n * 2 + 255) / 256) * 256;
    return p;
  };
  float* Wp1 = allocf(131072);
  float* Wp2 = allocf(65536);
  float* bai = allocf(4096);
  float* bah = allocf(4096);
  float* Wg1 = allocf(131072);
  float* bg1 = allocf(128);
  float* Wg2 = allocf(256);
  float* bdi = allocf(4096);
  float* bdh = allocf(4096);
  float* Wpr = allocf(227328);
  float* bpr = allocf(148);
  unsigned short* PWatt = allocu((size_t)NKB_ATT * 256 * 512);  // bf16 packed weights
  unsigned short* PWdec = allocu((size_t)NKB_DEC * 256 * 512);
  unsigned short* pre_bf = allocu((size_t)Tn * 64 * Pn);
  float* Patt = allocf((size_t)ACH * 64 * G4A);                 // 8 chunks
  float* Pdec = allocf((size_t)DCH * 64 * G4A);                 // 8 chunks
  // zero region: ac, dc, mean (f32) then attA, decA (bf16), all contiguous 256B-mult
  float* ac = allocf(65536);
  float* dc = allocf(65536);
  float* mean = allocf(64);
  unsigned short* attA = allocu((size_t)64 * KATT);   // 114688 elems
  unsigned short* decA = allocu((size_t)64 * KDEC);   // 163840 elems
  size_t fixed = off;
  size_t nDH = (size_t)Tn * 64 * Dn, nCX = (size_t)Tn * 64 * En;
  bool f32tier = (fixed + (nDH + nCX) * 4 <= ws_size);
  bool b16tier = (fixed + (nDH + nCX) * 2 <= ws_size);
  if (!f32tier && !b16tier) return;

  Ptrs P;
  P.Wp1=Wp1; P.Wp2=Wp2; P.bai=bai; P.bah=bah; P.Wg1=Wg1; P.bg1=bg1; P.Wg2=Wg2;
  P.bdi=bdi; P.bdh=bdh; P.Wpr=Wpr; P.bpr=bpr;
  P.PWatt=PWatt; P.PWdec=PWdec; P.pre_bf=pre_bf; P.attA=attA; P.decA=decA;
  P.Patt=Patt; P.Pdec=Pdec; P.ac=ac; P.dc=dc; P.mean=mean;
  size_t esz = f32tier ? 4 : 2;
  P.dh_all  = base + fixed;
  P.ctx_all = base + fixed + nDH * esz;
  P.mem = d_in[0]; P.din = d_in[1]; P.mlen = (const int*)d_in[2];
  P.w_ai = d_in[5]; P.w_ah = d_in[6]; P.w_di = d_in[12]; P.w_dh = d_in[13];
  P.flag = flag; P.out = d_out;

  k_detect<<<1, 256, 0, stream>>>(d_in[0], flag);

  struct CV { const void* s; float* d; long n; };
  const CV cv[11] = {
    {d_in[3], Wp1, 131072}, {d_in[4], Wp2, 65536},
    {d_in[7], bai, 4096}, {d_in[8], bah, 4096},
    {d_in[9], Wg1, 131072}, {d_in[10], bg1, 128}, {d_in[11], Wg2, 256},
    {d_in[14], bdi, 4096}, {d_in[15], bdh, 4096},
    {d_in[16], Wpr, 227328}, {d_in[17], bpr, 148},
  };
  for (int i = 0; i < 11; ++i) {
    long g = (cv[i].n + 255) / 256; if (g > 1024) g = 1024;
    k_convert<<<(int)g, 256, 0, stream>>>(cv[i].s, cv[i].d, cv[i].n, flag);
  }
  k_pack<<<(NKB_ATT + NKB_DEC) * 64, 256, 0, stream>>>(P);
  // zero: ac+dc+mean = 131136 f32; attA 114688 u16 = 57344 words; decA 163840 u16 = 81920 words
  k_zero_f32<<<512, 256, 0, stream>>>(ac, 131136 + 57344 + 81920);
  k_zero_aligns<<<2048, 256, 0, stream>>>(d_out, flag);

  if (f32tier) run_pipeline<float>(P, stream);
  else         run_pipeline<unsigned short>(P, stream);
}

// Round 12
// 15762.981 us; speedup vs baseline: 1.0602x; 1.0602x over previous
//
#include <hip/hip_runtime.h>
#include <math.h>

// ---------------- config ----------------
#define TF_PARTITIONABLE 1   // jax threefry_partitionable (default True since jax 0.4.36)

static constexpr int Bn=64, Ln=512, En=512, Tn=512, Sn=512, Pn=256, An=1024, Dn=1024, Gn=128, Vn=148;
static constexpr int G4A = 4096;            // 4*A == 4*D
static constexpr int KPROJ = Dn + En;       // 1536
static constexpr int KATT = 1792, KDEC = 2560;
static constexpr int ACH = 4, ACK = 448;    // att gates K = 4 chunks x 448 (2 substages)
static constexpr int DCH = 4, DCK = 640;    // dec gates K = 4 chunks x 640
static constexpr int NKB_ATT = KATT / 32;   // 56 k-blocks
static constexpr int NKB_DEC = KDEC / 32;   // 80
static constexpr long LOGITS_OFF = 0;
static constexpr long ALIGNS_OFF = (long)Bn*Tn*Vn;               // 4,849,664
static constexpr long PARAMS_OFF = ALIGNS_OFF + (long)Bn*Tn*Ln;  // 21,626,880

using s16x8 = __attribute__((ext_vector_type(8))) short;
using f32x4 = __attribute__((ext_vector_type(4))) float;

// ---------------- threefry2x32 (jax-exact) ----------------
struct TFo { unsigned a, b; };
static constexpr TFo htf(unsigned k1, unsigned k2, unsigned x0, unsigned x1) {
  unsigned ks2 = k1 ^ k2 ^ 0x1BD11BDAu;
  unsigned ks[3] = {k1, k2, ks2};
  const unsigned ra[4] = {13u,15u,26u,6u}, rb[4] = {17u,29u,16u,24u};
  x0 += k1; x1 += k2;
  for (int g = 0; g < 5; ++g) {
    const unsigned* r = (g % 2 == 0) ? ra : rb;
    for (int i = 0; i < 4; ++i) { x0 += x1; x1 = (x1 << r[i]) | (x1 >> (32u - r[i])); x1 ^= x0; }
    x0 += ks[(g+1)%3]; x1 += ks[(g+2)%3] + (unsigned)(g+1);
  }
  return TFo{x0, x1};
}
#if TF_PARTITIONABLE
static constexpr TFo DK1 = htf(0u,42u,0u,0u);
static constexpr TFo DK2 = htf(0u,42u,0u,1u);
#else
static constexpr TFo S02 = htf(0u,42u,0u,2u);
static constexpr TFo S13 = htf(0u,42u,1u,3u);
static constexpr TFo DK1 = TFo{S02.a, S13.a};
static constexpr TFo DK2 = TFo{S02.b, S13.b};
#endif

__device__ __forceinline__ void dtf(unsigned k1, unsigned k2, unsigned x0, unsigned x1,
                                    unsigned& o0, unsigned& o1) {
  unsigned ks2 = k1 ^ k2 ^ 0x1BD11BDAu;
#define TFR(r) { x0 += x1; x1 = (x1<<r)|(x1>>(32-r)); x1 ^= x0; }
  x0 += k1; x1 += k2;
  TFR(13) TFR(15) TFR(26) TFR(6)  x0 += k2;  x1 += ks2 + 1u;
  TFR(17) TFR(29) TFR(16) TFR(24) x0 += ks2; x1 += k1 + 2u;
  TFR(13) TFR(15) TFR(26) TFR(6)  x0 += k1;  x1 += k2 + 3u;
  TFR(17) TFR(29) TFR(16) TFR(24) x0 += k2;  x1 += ks2 + 4u;
  TFR(13) TFR(15) TFR(26) TFR(6)  x0 += ks2; x1 += k1 + 5u;
#undef TFR
  o0 = x0; o1 = x1;
}

__device__ __forceinline__ bool keepmask(unsigned ka, unsigned kb, unsigned j) {
#if TF_PARTITIONABLE
  unsigned o0, o1; dtf(ka, kb, 0u, j, o0, o1);
  return ((o0 ^ o1) >> 31) == 0u;
#else
  const unsigned H = 4202496u;  // (513*64*256)/2
  unsigned o0, o1;
  if (j < H) { dtf(ka, kb, j, j + H, o0, o1); return (o0 >> 31) == 0u; }
  else       { dtf(ka, kb, j - H, j, o0, o1); return (o1 >> 31) == 0u; }
#endif
}

// ---------------- dtype helpers ----------------
__device__ __forceinline__ float ldbf(const unsigned short* p, long i) {
  return __uint_as_float(((unsigned)p[i]) << 16);
}
__device__ __forceinline__ float bflo(unsigned q) { return __uint_as_float(q << 16); }
__device__ __forceinline__ float bfhi(unsigned q) { return __uint_as_float(q & 0xffff0000u); }
__device__ __forceinline__ unsigned short f2bf(float v) {
  unsigned x = __float_as_uint(v);
  return (unsigned short)((x + 0x7fffu + ((x >> 16) & 1u)) >> 16);  // RNE
}
__device__ __forceinline__ void store_out(void* out, long i, float v, int bf) {
  if (bf) ((unsigned short*)out)[i] = f2bf(v);
  else    ((float*)out)[i] = v;
}
__device__ __forceinline__ float st_load(const float* p, long i) { return p[i]; }
__device__ __forceinline__ float st_load(const unsigned short* p, long i) { return ldbf(p, i); }
__device__ __forceinline__ void st_store(float* p, long i, float v) { p[i] = v; }
__device__ __forceinline__ void st_store(unsigned short* p, long i, float v) { p[i] = f2bf(v); }
__device__ __forceinline__ float sigm(float x) { return 1.f / (1.f + expf(-x)); }
__device__ __forceinline__ void st4bf(unsigned short* p, float a, float b, float c, float d) {
  union { unsigned short u[4]; uint2 v; } q;
  q.u[0] = f2bf(a); q.u[1] = f2bf(b); q.u[2] = f2bf(c); q.u[3] = f2bf(d);
  *(uint2*)p = q.v;
}
__device__ __forceinline__ void st8bf(unsigned short* p, const float* h) {
  union { unsigned short u[8]; uint4 v; } q;
#pragma unroll
  for (int i = 0; i < 8; ++i) q.u[i] = f2bf(h[i]);
  *(uint4*)p = q.v;
}

// ---------------- pointer pack ----------------
struct Ptrs {
  const float *Wp1,*Wp2,*bai,*bah,*Wg1,*bg1,*Wg2,*bdi,*bdh,*Wpr,*bpr;
  unsigned short *PWatt,*PWdec,*pre_bf,*attA,*decA;   // decA: 2 slots of 64*KDEC
  float *Patt,*Pdec,*ac,*dc,*mean;
  void *dh_all,*ctx_all;
  const void *mem,*din,*w_ai,*w_ah,*w_di,*w_dh;
  const int *mlen; const int *flag; void *out;
};

// ---------------- utility kernels ----------------
__global__ __launch_bounds__(256) void k_detect(const void* mem, int* flag) {
  __shared__ int cnt;
  int tid = threadIdx.x;
  if (tid == 0) cnt = 0;
  __syncthreads();
  const unsigned short* p = (const unsigned short*)mem;
  int local = 0;
  for (int i = tid; i < 1024; i += 256) {
    float f = ldbf(p, 2L * i);
    if (f == f && fabsf(f) > 0.0009f && fabsf(f) < 16.f) local++;
  }
  atomicAdd(&cnt, local);
  __syncthreads();
  if (tid == 0) flag[0] = (cnt > 512) ? 1 : 0;
}

__global__ __launch_bounds__(256) void k_convert(const void* src, float* dst, long n, const int* flag) {
  int bf = *flag;
  long i0 = (long)blockIdx.x * 256 + threadIdx.x, stp = (long)gridDim.x * 256;
  if (bf) { const unsigned short* s = (const unsigned short*)src;
            for (long i = i0; i < n; i += stp) dst[i] = ldbf(s, i); }
  else    { const float* s = (const float*)src;
            for (long i = i0; i < n; i += stp) dst[i] = s[i]; }
}

__global__ __launch_bounds__(256) void k_zero_f32(float* p, long n) {
  for (long i = (long)blockIdx.x * 256 + threadIdx.x; i < n; i += (long)gridDim.x * 256) p[i] = 0.f;
}

__global__ __launch_bounds__(256) void k_zero_aligns(void* out, const int* flag) {
  int bf = *flag;
  unsigned* p; long n;
  if (bf) { p = (unsigned*)out + (ALIGNS_OFF >> 1); n = ((long)Bn*Tn*Ln) >> 1; }
  else    { p = (unsigned*)out + ALIGNS_OFF;        n = (long)Bn*Tn*Ln; }
  for (long i = (long)blockIdx.x * 256 + threadIdx.x; i < n; i += (long)gridDim.x * 256) p[i] = 0u;
}

// copy pre(0) into attA pre segment (prologue only)
__global__ __launch_bounds__(256) void k_precopy(Ptrs P) {
  int tid = threadIdx.x;
  for (int i = tid; i < 2048; i += 256) {
    int b = i >> 5, g = i & 31;
    *(uint4*)(P.attA + (long)b * KATT + g * 8) =
        *(const uint4*)(P.pre_bf + (long)b * Pn + g * 8);
  }
}

// ---------------- weight packing: bf16 B-fragment order ----------------
__global__ __launch_bounds__(256) void k_pack(Ptrs P) {
  __shared__ float s[32][65];
  int bid = blockIdx.x, tid = threadIdx.x;
  bool att = bid < NKB_ATT * 64;
  int lb = att ? bid : bid - NKB_ATT * 64;
  int kblk = lb >> 6, ng = lb & 63;
  int n0 = ng * 64;
  int bf = *P.flag;
  int split = att ? (Pn + En) : (An + En);
  const void* S0 = att ? P.w_ai : P.w_di;
  const void* S1 = att ? P.w_ah : P.w_dh;
  for (int i = tid; i < 2048; i += 256) {
    int kk = i >> 6, n = i & 63;
    int k = kblk * 32 + kk;
    const void* src = (k < split) ? S0 : S1;
    long idx = (long)(k < split ? k : k - split) * G4A + (n0 + n);
    s[kk][n] = bf ? ldbf((const unsigned short*)src, idx) : ((const float*)src)[idx];
  }
  __syncthreads();
  int lane = tid & 63, tb = tid >> 6;
  unsigned short r[8];
#pragma unroll
  for (int j = 0; j < 8; ++j)
    r[j] = f2bf(s[(lane >> 4) * 8 + j][tb * 16 + (lane & 15)]);
  unsigned short* out = (att ? P.PWatt : P.PWdec) +
      (((long)kblk * 256 + (ng * 4 + tb)) * 64 + lane) * 8;
  *(uint4*)out = *(const uint4*)r;
}

// ---------------- prenet (fused GEMM1+mask1+GEMM2+mask2) -> bf16 ----------------
__global__ __launch_bounds__(256) void k_prenet(Ptrs P, unsigned k1a, unsigned k1b,
                                                unsigned k2a, unsigned k2b) {
  __shared__ __align__(16) float x_s[32 * 17];
  __shared__ __align__(16) float W_s[16 * 256];
  __shared__ __align__(16) float h1_s[32 * 258];
  int bid = blockIdx.x, tid = threadIdx.x;
  int t = bid >> 1, half = bid & 1;
  int bf = *P.flag;
  int tc = tid & 63, tr = tid >> 6;
  int p0 = tc * 4, bl0 = tr * 8;
  float acc[8][4];
#pragma unroll
  for (int i = 0; i < 8; ++i) { acc[i][0]=0; acc[i][1]=0; acc[i][2]=0; acc[i][3]=0; }

  for (int kc = 0; kc < 32; ++kc) {
    __syncthreads();
    for (int i = tid; i < 32 * 16; i += 256) {
      int bl = i >> 4, kk = i & 15;
      int s = kc * 16 + kk;
      float v = 0.f;
      if (t > 0) {
        long idx = ((long)(half * 32 + bl) * Sn + s) * Tn + (t - 1);
        v = bf ? ldbf((const unsigned short*)P.din, idx) : ((const float*)P.din)[idx];
      }
      x_s[bl * 17 + kk] = v;
    }
    for (int i = tid; i < 16 * 256; i += 256) {
      int kk = i >> 8, p = i & 255;
      W_s[kk * 256 + p] = P.Wp1[(long)(kc * 16 + kk) * 256 + p];
    }
    __syncthreads();
    for (int kk = 0; kk < 16; ++kk) {
      float4 w = *(const float4*)(W_s + kk * 256 + p0);
#pragma unroll
      for (int i = 0; i < 8; ++i) {
        float x = x_s[(bl0 + i) * 17 + kk];
        acc[i][0] += x * w.x; acc[i][1] += x * w.y; acc[i][2] += x * w.z; acc[i][3] += x * w.w;
      }
    }
  }
#pragma unroll
  for (int i = 0; i < 8; ++i)
#pragma unroll
    for (int j = 0; j < 4; ++j) {
      int bl = bl0 + i, p = p0 + j, bg = half * 32 + bl;
      float v = fmaxf(acc[i][j], 0.f);
      unsigned ft = (unsigned)(((long)t * 64 + bg) * 256 + p);
      v = keepmask(k1a, k1b, ft) ? 2.f * v : 0.f;
      h1_s[bl * 258 + p] = v;
      acc[i][j] = 0.f;
    }
  __syncthreads();
  for (int kc = 0; kc < 16; ++kc) {
    __syncthreads();
    for (int i = tid; i < 16 * 256; i += 256) {
      int kk = i >> 8, p = i & 255;
      W_s[kk * 256 + p] = P.Wp2[(long)(kc * 16 + kk) * 256 + p];
    }
    __syncthreads();
    for (int kk = 0; kk < 16; ++kk) {
      float4 w = *(const float4*)(W_s + kk * 256 + p0);
      int s = kc * 16 + kk;
#pragma unroll
      for (int i = 0; i < 8; ++i) {
        float x = h1_s[(bl0 + i) * 258 + s];
        acc[i][0] += x * w.x; acc[i][1] += x * w.y; acc[i][2] += x * w.z; acc[i][3] += x * w.w;
      }
    }
  }
#pragma unroll
  for (int i = 0; i < 8; ++i)
#pragma unroll
    for (int j = 0; j < 4; ++j) {
      int bg = half * 32 + bl0 + i, p = p0 + j;
      float v = fmaxf(acc[i][j], 0.f);
      unsigned ft = (unsigned)(((long)t * 64 + bg) * 256 + p);
      v = keepmask(k2a, k2b, ft) ? 2.f * v : 0.f;
      P.pre_bf[((long)t * 64 + bg) * 256 + p] = f2bf(v);
    }
}

// ---------------- GEMM body (R10-proven): LDS-staged contiguous A, 2 substages, 4-deep B ----------------
template<bool ATT>
__device__ __forceinline__ void dev_gemm(const Ptrs& P, int cg, int kc,
                                         const unsigned short* A, unsigned short* a_lds) {
  constexpr int CK    = ATT ? ACK : DCK;      // 448 / 640
  constexpr int SUBK  = CK / 2;               // 224 / 320
  constexpr int NKS   = SUBK / 32;            // 7 / 10
  constexpr int PITCH = SUBK + 8;             // <=2-way LDS bank aliasing (free)
  constexpr int GPR   = SUBK / 8;             // 16B groups per row: 28 / 40
  constexpr int KSTR  = ATT ? KATT : KDEC;    // A row stride (contiguous packed)
  int tid = threadIdx.x;
  int lane = tid & 63, w = tid >> 6;
  int nblk = cg * 4 + w;
  const unsigned short* PW = ATT ? P.PWatt : P.PWdec;
  int rlo = lane & 15, khi8 = (lane >> 4) * 8;
  const int k0 = kc * CK;

  f32x4 acc[4];
#pragma unroll
  for (int i = 0; i < 4; ++i) acc[i] = f32x4{0.f, 0.f, 0.f, 0.f};

#pragma unroll
  for (int sub = 0; sub < 2; ++sub) {
    const int kk0 = k0 + sub * SUBK;
    __syncthreads();
#pragma unroll
    for (int i = 0; i < GPR / 4; ++i) {         // branch-free coalesced staging
      int g = tid + i * 256;
      int row = g / GPR, kg = (g - row * GPR) * 8;
      *(uint4*)(a_lds + row * PITCH + kg) = *(const uint4*)(A + (long)row * KSTR + kk0 + kg);
    }
    __syncthreads();
    const unsigned short* bptr = PW + (((long)(kk0 >> 5) * 256 + nblk) * 64 + lane) * 8;
    s16x8 br[4];
#pragma unroll
    for (int i = 0; i < 4; ++i) br[i] = *(const s16x8*)(bptr + (long)i * 131072);
#pragma unroll
    for (int kb = 0; kb < NKS; ++kb) {
      s16x8 bcur = br[kb & 3];
      if (kb + 4 < NKS) br[kb & 3] = *(const s16x8*)(bptr + (long)(kb + 4) * 131072);
      int abase = kb * 32 + khi8;
#pragma unroll
      for (int mb = 0; mb < 4; ++mb) {
        s16x8 a = *(const s16x8*)(a_lds + (mb * 16 + rlo) * PITCH + abase);
        acc[mb] = __builtin_amdgcn_mfma_f32_16x16x32_bf16(a, bcur, acc[mb], 0, 0, 0);
      }
    }
  }
  float* Pout = (ATT ? P.Patt : P.Pdec) + (long)kc * 64 * G4A;
  int col = nblk * 16 + rlo, rbase = (lane >> 4) * 4;
#pragma unroll
  for (int mb = 0; mb < 4; ++mb)
#pragma unroll
    for (int r = 0; r < 4; ++r)
      Pout[(long)(mb * 16 + rbase + r) * G4A + col] = acc[mb][r];
}

// ---------------- attpw(t): att LSTM pointwise + GMM + alpha + ctx ----------------
template<typename ST>
__device__ __forceinline__ void dev_attpw(const Ptrs& P, int t, int b,
    float* ah_s, float* red_s, float* tanh_s, float* bc_s, float* alpha_s) {
  int tid = threadIdx.x;
  int bf = *P.flag;
  unsigned short* decAs = P.decA + (long)(t & 1) * 64 * KDEC;
  // copy pre(t+1) into attA pre segment (for att-gates(t+1))
  if (t + 1 < Tn && tid < 32) {
    *(uint4*)(P.attA + (long)b * KATT + tid * 8) =
        *(const uint4*)(P.pre_bf + ((long)(t + 1) * 64 + b) * Pn + tid * 8);
  }
  int u0 = tid * 4;
  float gv[4][4];
#pragma unroll
  for (int gt = 0; gt < 4; ++gt) {
    float4 a = *(const float4*)(P.bai + gt * 1024 + u0);
    float4 c = *(const float4*)(P.bah + gt * 1024 + u0);
    gv[gt][0] = a.x + c.x; gv[gt][1] = a.y + c.y; gv[gt][2] = a.z + c.z; gv[gt][3] = a.w + c.w;
  }
#pragma unroll
  for (int kc = 0; kc < ACH; ++kc) {
    const float* pa = P.Patt + ((long)kc * 64 + b) * G4A + u0;
#pragma unroll
    for (int gt = 0; gt < 4; ++gt) {
      float4 v = *(const float4*)(pa + gt * 1024);
      gv[gt][0] += v.x; gv[gt][1] += v.y; gv[gt][2] += v.z; gv[gt][3] += v.w;
    }
  }
  float4 oc = *(const float4*)(P.ac + b * 1024 + u0);
  float oldc[4] = {oc.x, oc.y, oc.z, oc.w};
  float hh[4], cc[4];
#pragma unroll
  for (int i = 0; i < 4; ++i) {
    float ii = sigm(gv[0][i]), ff = sigm(gv[1][i]), oo = sigm(gv[3][i]);
    cc[i] = ff * oldc[i] + ii * tanhf(gv[2][i]);
    hh[i] = oo * tanhf(cc[i]);
    ah_s[u0 + i] = hh[i];
  }
  *(float4*)(P.ac + b * 1024 + u0) = make_float4(cc[0], cc[1], cc[2], cc[3]);
  st4bf(P.attA + (long)b * KATT + 768 + u0, hh[0], hh[1], hh[2], hh[3]);
  st4bf(decAs + (long)b * KDEC + u0,        hh[0], hh[1], hh[2], hh[3]);
  __syncthreads();
  // GMM hidden: tanh(ah @ W_g1 + b_g1)
  {
    int g = tid & 127, hf = tid >> 7;
    const float* wg = P.Wg1 + g;
    float a0 = 0.f, a1 = 0.f;
    int ub = hf * 512;
    for (int u = ub; u < ub + 512; u += 2) {
      a0 += ah_s[u]     * wg[(long)u * 128];
      a1 += ah_s[u + 1] * wg[(long)(u + 1) * 128];
    }
    red_s[tid] = a0 + a1;
  }
  __syncthreads();
  if (tid < 128) tanh_s[tid] = tanhf(red_s[tid] + red_s[tid + 128] + P.bg1[tid]);
  __syncthreads();
  if (tid < 64) {
    float tv0 = tanh_s[tid], tv1 = tanh_s[tid + 64];
    float h0 = tv0 * P.Wg2[2 * tid]     + tv1 * P.Wg2[2 * (tid + 64)];
    float h1 = tv0 * P.Wg2[2 * tid + 1] + tv1 * P.Wg2[2 * (tid + 64) + 1];
#pragma unroll
    for (int o = 32; o; o >>= 1) { h0 += __shfl_down(h0, o); h1 += __shfl_down(h1, o); }
    if (tid == 0) {
      float m  = P.mean[b] + expf(h0) * 8.f;
      float sc = expf(h1) * 8.f;
      P.mean[b] = m;
      long pidx = PARAMS_OFF + ((long)b * Tn + t) * 2;
      store_out(P.out, pidx, h0, bf);
      store_out(P.out, pidx + 1, h1, bf);
      bc_s[0] = m; bc_s[1] = sc;
    }
  }
  __syncthreads();
  float m = bc_s[0], sc = bc_s[1];
  int len = P.mlen[b];
  int ci = (int)floorf(fminf(m, 100000.f));
  int l0 = ci - 80; if (l0 < 0) l0 = 0;
  int l1 = ci + 81; if (l1 > len) l1 = len;
  float inv2 = 0.5f / (sc * sc);
  float invZ = 1.f / (2.50662827463100050242f * sc);
  for (int l = l0 + tid; l < l1; l += 256) {
    float d = (float)l - m;
    float al = expf(-d * d * inv2) * invZ;
    alpha_s[l - l0] = al;
    store_out(P.out, ALIGNS_OFF + ((long)b * Tn + t) * Ln + l, al, bf);
  }
  __syncthreads();
  int nl = l1 - l0;
  ST* ctx_all = (ST*)P.ctx_all;
  int e0 = tid * 2;
  float s0 = 0.f, s1 = 0.f;
  if (bf) {
    const unsigned* mem = (const unsigned*)((const unsigned short*)P.mem +
                                            ((long)b * Ln + l0) * En + e0);
    for (int l = 0; l < nl; ++l) {
      float al = alpha_s[l];
      unsigned q = mem[(long)l * (En / 2)];
      s0 += al * bflo(q);
      s1 += al * bfhi(q);
    }
  } else {
    const float* mem = (const float*)P.mem + ((long)b * Ln + l0) * En + e0;
    for (int l = 0; l < nl; ++l) {
      float al = alpha_s[l];
      float2 v = *(const float2*)(mem + (long)l * En);
      s0 += al * v.x;
      s1 += al * v.y;
    }
  }
  unsigned q = (unsigned)f2bf(s0) | ((unsigned)f2bf(s1) << 16);
  *(unsigned*)(P.attA + (long)b * KATT + 256 + e0) = q;
  *(unsigned*)(decAs + (long)b * KDEC + 1024 + e0) = q;
  st_store(ctx_all, ((long)t * 64 + b) * En + e0, s0);
  st_store(ctx_all, ((long)t * 64 + b) * En + e0 + 1, s1);
}

// ---------------- decpw(tau): dec LSTM pointwise, 2 batch rows per block ----------------
// writes dh(tau) into decA slot (tau+1)&1 (consumed by dec-gates(tau+1))
template<typename ST>
__device__ __forceinline__ void dev_decpw(const Ptrs& P, int tau, int bb) {
  int tid = threadIdx.x;
  int b = bb * 2 + (tid >> 7);
  int u0 = (tid & 127) * 8;
  ST* dh_all = (ST*)P.dh_all;
  unsigned short* decAs = P.decA + (long)((tau + 1) & 1) * 64 * KDEC;
  float gv[4][8];
#pragma unroll
  for (int gt = 0; gt < 4; ++gt) {
    float4 a0 = *(const float4*)(P.bdi + gt * 1024 + u0);
    float4 a1 = *(const float4*)(P.bdi + gt * 1024 + u0 + 4);
    float4 c0 = *(const float4*)(P.bdh + gt * 1024 + u0);
    float4 c1 = *(const float4*)(P.bdh + gt * 1024 + u0 + 4);
    gv[gt][0] = a0.x + c0.x; gv[gt][1] = a0.y + c0.y; gv[gt][2] = a0.z + c0.z; gv[gt][3] = a0.w + c0.w;
    gv[gt][4] = a1.x + c1.x; gv[gt][5] = a1.y + c1.y; gv[gt][6] = a1.z + c1.z; gv[gt][7] = a1.w + c1.w;
  }
#pragma unroll
  for (int kc = 0; kc < DCH; ++kc) {
    const float* pd = P.Pdec + ((long)kc * 64 + b) * G4A + u0;
#pragma unroll
    for (int gt = 0; gt < 4; ++gt) {
      float4 v0 = *(const float4*)(pd + gt * 1024);
      float4 v1 = *(const float4*)(pd + gt * 1024 + 4);
      gv[gt][0] += v0.x; gv[gt][1] += v0.y; gv[gt][2] += v0.z; gv[gt][3] += v0.w;
      gv[gt][4] += v1.x; gv[gt][5] += v1.y; gv[gt][6] += v1.z; gv[gt][7] += v1.w;
    }
  }
  float4 oc0 = *(const float4*)(P.dc + b * 1024 + u0);
  float4 oc1 = *(const float4*)(P.dc + b * 1024 + u0 + 4);
  float oldc[8] = {oc0.x, oc0.y, oc0.z, oc0.w, oc1.x, oc1.y, oc1.z, oc1.w};
  float hh[8], cc[8];
#pragma unroll
  for (int i = 0; i < 8; ++i) {
    float ii = sigm(gv[0][i]), ff = sigm(gv[1][i]), oo = sigm(gv[3][i]);
    cc[i] = ff * oldc[i] + ii * tanhf(gv[2][i]);
    hh[i] = oo * tanhf(cc[i]);
  }
  *(float4*)(P.dc + b * 1024 + u0)     = make_float4(cc[0], cc[1], cc[2], cc[3]);
  *(float4*)(P.dc + b * 1024 + u0 + 4) = make_float4(cc[4], cc[5], cc[6], cc[7]);
  st8bf(decAs + (long)b * KDEC + 1536 + u0, hh);
#pragma unroll
  for (int i = 0; i < 8; ++i)
    st_store(dh_all, ((long)tau * 64 + b) * 1024 + u0 + i, hh[i]);
}

// ---------------- K1(t): dec-gates(t-1) [0..255] || attpw(t) [256..319] ----------------
template<typename ST>
__global__ __launch_bounds__(256) void k_phase1(Ptrs P, int t) {
  __shared__ __align__(16) unsigned short a_lds[64 * 328];  // dec pitch (42 KB)
  __shared__ float ah_s[1024];
  __shared__ float red_s[256];
  __shared__ float tanh_s[128];
  __shared__ float bc_s[2];
  __shared__ float alpha_s[176];
  int bid = blockIdx.x;
  if (bid < 256) {
    int tau = t - 1;
    if (tau < 0 || tau >= Tn) return;
    const unsigned short* A = P.decA + (long)(tau & 1) * 64 * KDEC;
    dev_gemm<false>(P, bid >> 2, bid & 3, A, a_lds);
  } else {
    if (t >= Tn) return;
    dev_attpw<ST>(P, t, bid - 256, ah_s, red_s, tanh_s, bc_s, alpha_s);
  }
}

// ---------------- K2(t): att-gates(t+1) [0..255] || decpw(t-1) [256..287] ----------------
template<typename ST>
__global__ __launch_bounds__(256) void k_phase2(Ptrs P, int t) {
  __shared__ __align__(16) unsigned short a_lds[64 * 232];  // att pitch (29 KB)
  int bid = blockIdx.x;
  if (bid < 256) {
    if (t + 1 < 0 || t + 1 >= Tn) return;
    dev_gemm<true>(P, bid >> 2, bid & 3, P.attA, a_lds);
  } else {
    int tau = t - 1;
    if (tau < 0 || tau >= Tn) return;
    dev_decpw<ST>(P, tau, bid - 256);
  }
}

// ---------------- final projection: logits = [dh, ctx] @ W_proj + b ----------------
template<typename ST>
__global__ __launch_bounds__(256) void k_proj(Ptrs P) {
  __shared__ __align__(16) float A_s[64][65];
  __shared__ __align__(16) float W_s[64 * 160];
  int t = blockIdx.x, tid = threadIdx.x;
  int bf = *P.flag;
  const ST* dh_all = (const ST*)P.dh_all;
  const ST* ctx_all = (const ST*)P.ctx_all;
  int tc = tid & 15, tr = tid >> 4;
  int c0 = tc * 10, b0 = tr * 4;
  float acc[4][10];
#pragma unroll
  for (int i = 0; i < 4; ++i)
#pragma unroll
    for (int j = 0; j < 10; ++j) acc[i][j] = 0.f;
  for (int k0 = 0; k0 < KPROJ; k0 += 64) {
    __syncthreads();
    for (int i = tid; i < 64 * 64; i += 256) {
      int b = i >> 6, kk = i & 63;
      int k = k0 + kk;
      float v = (k < Dn) ? st_load(dh_all, ((long)t * 64 + b) * Dn + k)
                         : st_load(ctx_all, ((long)t * 64 + b) * En + (k - Dn));
      A_s[b][kk] = v;
    }
    for (int i = tid; i < 64 * 160; i += 256) {
      int kk = i / 160, c = i - kk * 160;
      W_s[kk * 160 + c] = (c < Vn) ? P.Wpr[(long)(k0 + kk) * Vn + c] : 0.f;
    }
    __syncthreads();
    for (int kk = 0; kk < 64; ++kk) {
      float xs[4];
#pragma unroll
      for (int i = 0; i < 4; ++i) xs[i] = A_s[b0 + i][kk];
#pragma unroll
      for (int j = 0; j < 10; ++j) {
        float w = W_s[kk * 160 + c0 + j];
#pragma unroll
        for (int i = 0; i < 4; ++i) acc[i][j] += xs[i] * w;
      }
    }
  }
#pragma unroll
  for (int i = 0; i < 4; ++i)
#pragma unroll
    for (int j = 0; j < 10; ++j) {
      int c = c0 + j;
      if (c < Vn) {
        int b = b0 + i;
        store_out(P.out, LOGITS_OFF + ((long)b * Tn + t) * Vn + c, acc[i][j] + P.bpr[c], bf);
      }
    }
}

// ---------------- host ----------------
template<typename ST>
static void run_pipeline(const Ptrs& P, hipStream_t stream) {
  k_prenet<<<Tn * 2, 256, 0, stream>>>(P, DK1.a, DK1.b, DK2.a, DK2.b);
  k_precopy<<<1, 256, 0, stream>>>(P);                  // pre(0) -> attA
  k_phase2<ST><<<288, 256, 0, stream>>>(P, -1);         // prologue: att-gates(0)
  for (int t = 0; t <= Tn; ++t) {
    k_phase1<ST><<<320, 256, 0, stream>>>(P, t);        // dec-gates(t-1) || attpw(t)
    k_phase2<ST><<<288, 256, 0, stream>>>(P, t);        // att-gates(t+1) || decpw(t-1)
  }
  k_proj<ST><<<Tn, 256, 0, stream>>>(P);
}

extern "C" void kernel_launch(void* const* d_in, const int* in_sizes, int n_in,
                              void* d_out, int out_size, void* d_ws, size_t ws_size,
                              hipStream_t stream) {
  (void)in_sizes; (void)n_in; (void)out_size;
  char* base = (char*)d_ws;
  int* flag = (int*)base;
  size_t off = 256;
  auto allocf = [&](size_t n) -> float* {
    float* p = (float*)(base + off);
    off += ((n * 4 + 255) / 256) * 256;
    return p;
  };
  auto allocu = [&](size_t n) -> unsigned short* {
    unsigned short* p = (unsigned short*)(base + off);
    off += ((n * 2 + 255) / 256) * 256;
    return p;
  };
  float* Wp1 = allocf(131072);
  float* Wp2 = allocf(65536);
  float* bai = allocf(4096);
  float* bah = allocf(4096);
  float* Wg1 = allocf(131072);
  float* bg1 = allocf(128);
  float* Wg2 = allocf(256);
  float* bdi = allocf(4096);
  float* bdh = allocf(4096);
  float* Wpr = allocf(227328);
  float* bpr = allocf(148);
  unsigned short* PWatt = allocu((size_t)NKB_ATT * 256 * 512);  // bf16 packed weights
  unsigned short* PWdec = allocu((size_t)NKB_DEC * 256 * 512);
  unsigned short* pre_bf = allocu((size_t)Tn * 64 * Pn);
  float* Patt = allocf((size_t)ACH * 64 * G4A);
  float* Pdec = allocf((size_t)DCH * 64 * G4A);
  // zero region: ac, dc, mean (f32) then attA, decA[2] (bf16), contiguous 256B-mult
  float* ac = allocf(65536);
  float* dc = allocf(65536);
  float* mean = allocf(64);
  unsigned short* attA = allocu((size_t)64 * KATT);       // 114688 elems
  unsigned short* decA = allocu((size_t)2 * 64 * KDEC);   // 327680 elems (2 slots)
  size_t fixed = off;
  size_t nDH = (size_t)Tn * 64 * Dn, nCX = (size_t)Tn * 64 * En;
  bool f32tier = (fixed + (nDH + nCX) * 4 <= ws_size);
  bool b16tier = (fixed + (nDH + nCX) * 2 <= ws_size);
  if (!f32tier && !b16tier) return;

  Ptrs P;
  P.Wp1=Wp1; P.Wp2=Wp2; P.bai=bai; P.bah=bah; P.Wg1=Wg1; P.bg1=bg1; P.Wg2=Wg2;
  P.bdi=bdi; P.bdh=bdh; P.Wpr=Wpr; P.bpr=bpr;
  P.PWatt=PWatt; P.PWdec=PWdec; P.pre_bf=pre_bf; P.attA=attA; P.decA=decA;
  P.Patt=Patt; P.Pdec=Pdec; P.ac=ac; P.dc=dc; P.mean=mean;
  size_t esz = f32tier ? 4 : 2;
  P.dh_all  = base + fixed;
  P.ctx_all = base + fixed + nDH * esz;
  P.mem = d_in[0]; P.din = d_in[1]; P.mlen = (const int*)d_in[2];
  P.w_ai = d_in[5]; P.w_ah = d_in[6]; P.w_di = d_in[12]; P.w_dh = d_in[13];
  P.flag = flag; P.out = d_out;

  k_detect<<<1, 256, 0, stream>>>(d_in[0], flag);

  struct CV { const void* s; float* d; long n; };
  const CV cv[11] = {
    {d_in[3], Wp1, 131072}, {d_in[4], Wp2, 65536},
    {d_in[7], bai, 4096}, {d_in[8], bah, 4096},
    {d_in[9], Wg1, 131072}, {d_in[10], bg1, 128}, {d_in[11], Wg2, 256},
    {d_in[14], bdi, 4096}, {d_in[15], bdh, 4096},
    {d_in[16], Wpr, 227328}, {d_in[17], bpr, 148},
  };
  for (int i = 0; i < 11; ++i) {
    long g = (cv[i].n + 255) / 256; if (g > 1024) g = 1024;
    k_convert<<<(int)g, 256, 0, stream>>>(cv[i].s, cv[i].d, cv[i].n, flag);
  }
  k_pack<<<(NKB_ATT + NKB_DEC) * 64, 256, 0, stream>>>(P);
  // zero: ac+dc+mean = 131136 f32; attA 114688 u16 = 57344 words; decA 327680 u16 = 163840 words
  k_zero_f32<<<512, 256, 0, stream>>>(ac, 131136 + 57344 + 163840);
  k_zero_aligns<<<2048, 256, 0, stream>>>(d_out, flag);

  if (f32tier) run_pipeline<float>(P, stream);
  else         run_pipeline<unsigned short>(P, stream);
}

// Round 13
// 15310.469 us; speedup vs baseline: 1.0915x; 1.0296x over previous
//
#include <hip/hip_runtime.h>
#include <math.h>

// ---------------- config ----------------
#define TF_PARTITIONABLE 1   // jax threefry_partitionable (default True since jax 0.4.36)

static constexpr int Bn=64, Ln=512, En=512, Tn=512, Sn=512, Pn=256, An=1024, Dn=1024, Gn=128, Vn=148;
static constexpr int G4A = 4096;            // 4*A == 4*D
static constexpr int KPROJ = Dn + En;       // 1536
static constexpr int KATT = 1792, KDEC = 2560;
static constexpr int ACH = 4, ACK = 448;    // att gates K = 4 chunks x 448 (2 substages)
static constexpr int DCH = 4, DCK = 640;    // dec gates K = 4 chunks x 640
static constexpr int NKB_ATT = KATT / 32;   // 56 k-blocks
static constexpr int NKB_DEC = KDEC / 32;   // 80
static constexpr long LOGITS_OFF = 0;
static constexpr long ALIGNS_OFF = (long)Bn*Tn*Vn;               // 4,849,664
static constexpr long PARAMS_OFF = ALIGNS_OFF + (long)Bn*Tn*Ln;  // 21,626,880

using s16x8 = __attribute__((ext_vector_type(8))) short;
using f32x4 = __attribute__((ext_vector_type(4))) float;

// ---------------- threefry2x32 (jax-exact) ----------------
struct TFo { unsigned a, b; };
static constexpr TFo htf(unsigned k1, unsigned k2, unsigned x0, unsigned x1) {
  unsigned ks2 = k1 ^ k2 ^ 0x1BD11BDAu;
  unsigned ks[3] = {k1, k2, ks2};
  const unsigned ra[4] = {13u,15u,26u,6u}, rb[4] = {17u,29u,16u,24u};
  x0 += k1; x1 += k2;
  for (int g = 0; g < 5; ++g) {
    const unsigned* r = (g % 2 == 0) ? ra : rb;
    for (int i = 0; i < 4; ++i) { x0 += x1; x1 = (x1 << r[i]) | (x1 >> (32u - r[i])); x1 ^= x0; }
    x0 += ks[(g+1)%3]; x1 += ks[(g+2)%3] + (unsigned)(g+1);
  }
  return TFo{x0, x1};
}
#if TF_PARTITIONABLE
static constexpr TFo DK1 = htf(0u,42u,0u,0u);
static constexpr TFo DK2 = htf(0u,42u,0u,1u);
#else
static constexpr TFo S02 = htf(0u,42u,0u,2u);
static constexpr TFo S13 = htf(0u,42u,1u,3u);
static constexpr TFo DK1 = TFo{S02.a, S13.a};
static constexpr TFo DK2 = TFo{S02.b, S13.b};
#endif

__device__ __forceinline__ void dtf(unsigned k1, unsigned k2, unsigned x0, unsigned x1,
                                    unsigned& o0, unsigned& o1) {
  unsigned ks2 = k1 ^ k2 ^ 0x1BD11BDAu;
#define TFR(r) { x0 += x1; x1 = (x1<<r)|(x1>>(32-r)); x1 ^= x0; }
  x0 += k1; x1 += k2;
  TFR(13) TFR(15) TFR(26) TFR(6)  x0 += k2;  x1 += ks2 + 1u;
  TFR(17) TFR(29) TFR(16) TFR(24) x0 += ks2; x1 += k1 + 2u;
  TFR(13) TFR(15) TFR(26) TFR(6)  x0 += k1;  x1 += k2 + 3u;
  TFR(17) TFR(29) TFR(16) TFR(24) x0 += k2;  x1 += ks2 + 4u;
  TFR(13) TFR(15) TFR(26) TFR(6)  x0 += ks2; x1 += k1 + 5u;
#undef TFR
  o0 = x0; o1 = x1;
}

__device__ __forceinline__ bool keepmask(unsigned ka, unsigned kb, unsigned j) {
#if TF_PARTITIONABLE
  unsigned o0, o1; dtf(ka, kb, 0u, j, o0, o1);
  return ((o0 ^ o1) >> 31) == 0u;
#else
  const unsigned H = 4202496u;  // (513*64*256)/2
  unsigned o0, o1;
  if (j < H) { dtf(ka, kb, j, j + H, o0, o1); return (o0 >> 31) == 0u; }
  else       { dtf(ka, kb, j - H, j, o0, o1); return (o1 >> 31) == 0u; }
#endif
}

// ---------------- dtype helpers ----------------
__device__ __forceinline__ float ldbf(const unsigned short* p, long i) {
  return __uint_as_float(((unsigned)p[i]) << 16);
}
__device__ __forceinline__ float bflo(unsigned q) { return __uint_as_float(q << 16); }
__device__ __forceinline__ float bfhi(unsigned q) { return __uint_as_float(q & 0xffff0000u); }
__device__ __forceinline__ unsigned short f2bf(float v) {
  unsigned x = __float_as_uint(v);
  return (unsigned short)((x + 0x7fffu + ((x >> 16) & 1u)) >> 16);  // RNE
}
__device__ __forceinline__ void store_out(void* out, long i, float v, int bf) {
  if (bf) ((unsigned short*)out)[i] = f2bf(v);
  else    ((float*)out)[i] = v;
}
__device__ __forceinline__ float st_load(const float* p, long i) { return p[i]; }
__device__ __forceinline__ float st_load(const unsigned short* p, long i) { return ldbf(p, i); }
__device__ __forceinline__ void st_store(float* p, long i, float v) { p[i] = v; }
__device__ __forceinline__ void st_store(unsigned short* p, long i, float v) { p[i] = f2bf(v); }
__device__ __forceinline__ float sigm(float x) { return 1.f / (1.f + expf(-x)); }
__device__ __forceinline__ void st4bf(unsigned short* p, float a, float b, float c, float d) {
  union { unsigned short u[4]; uint2 v; } q;
  q.u[0] = f2bf(a); q.u[1] = f2bf(b); q.u[2] = f2bf(c); q.u[3] = f2bf(d);
  *(uint2*)p = q.v;
}
__device__ __forceinline__ void st8bf(unsigned short* p, const float* h) {
  union { unsigned short u[8]; uint4 v; } q;
#pragma unroll
  for (int i = 0; i < 8; ++i) q.u[i] = f2bf(h[i]);
  *(uint4*)p = q.v;
}

// ---------------- pointer pack ----------------
struct Ptrs {
  const float *Wp1,*Wp2,*bai,*bah,*Wg1,*bg1,*Wg2,*bdi,*bdh,*Wpr,*bpr;
  unsigned short *PWatt,*PWdec,*pre_bf,*attA,*decA,*xT;
  float *Patt,*Pdec,*ac,*dc,*mean;
  void *dh_all,*ctx_all;
  const void *mem,*din,*w_ai,*w_ah,*w_di,*w_dh;
  const int *mlen; const int *flag; void *out;
};

// ---------------- utility kernels ----------------
__global__ __launch_bounds__(256) void k_detect(const void* mem, int* flag) {
  __shared__ int cnt;
  int tid = threadIdx.x;
  if (tid == 0) cnt = 0;
  __syncthreads();
  const unsigned short* p = (const unsigned short*)mem;
  int local = 0;
  for (int i = tid; i < 1024; i += 256) {
    float f = ldbf(p, 2L * i);
    if (f == f && fabsf(f) > 0.0009f && fabsf(f) < 16.f) local++;
  }
  atomicAdd(&cnt, local);
  __syncthreads();
  if (tid == 0) flag[0] = (cnt > 512) ? 1 : 0;
}

__global__ __launch_bounds__(256) void k_convert(const void* src, float* dst, long n, const int* flag) {
  int bf = *flag;
  long i0 = (long)blockIdx.x * 256 + threadIdx.x, stp = (long)gridDim.x * 256;
  if (bf) { const unsigned short* s = (const unsigned short*)src;
            for (long i = i0; i < n; i += stp) dst[i] = ldbf(s, i); }
  else    { const float* s = (const float*)src;
            for (long i = i0; i < n; i += stp) dst[i] = s[i]; }
}

__global__ __launch_bounds__(256) void k_zero_f32(float* p, long n) {
  for (long i = (long)blockIdx.x * 256 + threadIdx.x; i < n; i += (long)gridDim.x * 256) p[i] = 0.f;
}

__global__ __launch_bounds__(256) void k_zero_aligns(void* out, const int* flag) {
  int bf = *flag;
  unsigned* p; long n;
  if (bf) { p = (unsigned*)out + (ALIGNS_OFF >> 1); n = ((long)Bn*Tn*Ln) >> 1; }
  else    { p = (unsigned*)out + ALIGNS_OFF;        n = (long)Bn*Tn*Ln; }
  for (long i = (long)blockIdx.x * 256 + threadIdx.x; i < n; i += (long)gridDim.x * 256) p[i] = 0u;
}

// copy pre(0) into attA pre segment (prologue only)
__global__ __launch_bounds__(256) void k_precopy(Ptrs P) {
  int tid = threadIdx.x;
  for (int i = tid; i < 2048; i += 256) {
    int b = i >> 5, g = i & 31;
    *(uint4*)(P.attA + (long)b * KATT + g * 8) =
        *(const uint4*)(P.pre_bf + (long)b * Pn + g * 8);
  }
}

// ---------------- transpose decoder_inputs (B,S,T) -> xT[t][b][s] bf16 ----------------
// xT row t = prenet input at step t: t=0 -> zeros (go frame); t>=1 -> din[b][:,t-1].
// grid = 64 b x 16 s-chunks (32 s each). Coalesced reads along T, writes along S.
__global__ __launch_bounds__(256) void k_xpose(Ptrs P) {
  __shared__ unsigned short tile[32][520];
  int bid = blockIdx.x, tid = threadIdx.x;
  int b = bid >> 4, s0 = (bid & 15) * 32;
  int bf = *P.flag;
  if (bf) {
    const unsigned short* din = (const unsigned short*)P.din;
    for (int i = tid; i < 32 * 512; i += 256) {
      int si = i >> 9, t = i & 511;
      tile[si][t] = din[((long)b * Sn + s0 + si) * Tn + t];
    }
  } else {
    const float* din = (const float*)P.din;
    for (int i = tid; i < 32 * 512; i += 256) {
      int si = i >> 9, t = i & 511;
      tile[si][t] = f2bf(din[((long)b * Sn + s0 + si) * Tn + t]);
    }
  }
  __syncthreads();
  // write rows t+1 (skip t=511 -> row 512 unused); 8 bf16 per write
  for (int i = tid; i < 512 * 4; i += 256) {
    int t = i >> 2, sg = i & 3;
    if (t >= 511) continue;
    union { unsigned short u[8]; uint4 v; } q;
#pragma unroll
    for (int j = 0; j < 8; ++j) q.u[j] = tile[sg * 8 + j][t];
    *(uint4*)(P.xT + ((long)(t + 1) * 64 + b) * Sn + s0 + sg * 8) = q.v;
  }
  // zero go-frame row (t=0)
  if (tid < 4) {
    uint4 z = make_uint4(0u, 0u, 0u, 0u);
    *(uint4*)(P.xT + (long)b * Sn + s0 + tid * 8) = z;
  }
}

// ---------------- weight packing: bf16 B-fragment order ----------------
// PW[kblk][nblk][lane][8]: lane l elem j <-> W[kblk*32 + (l>>4)*8 + j][nblk*16 + (l&15)]
__global__ __launch_bounds__(256) void k_pack(Ptrs P) {
  __shared__ float s[32][65];
  int bid = blockIdx.x, tid = threadIdx.x;
  bool att = bid < NKB_ATT * 64;
  int lb = att ? bid : bid - NKB_ATT * 64;
  int kblk = lb >> 6, ng = lb & 63;
  int n0 = ng * 64;
  int bf = *P.flag;
  int split = att ? (Pn + En) : (An + En);
  const void* S0 = att ? P.w_ai : P.w_di;
  const void* S1 = att ? P.w_ah : P.w_dh;
  for (int i = tid; i < 2048; i += 256) {
    int kk = i >> 6, n = i & 63;
    int k = kblk * 32 + kk;
    const void* src = (k < split) ? S0 : S1;
    long idx = (long)(k < split ? k : k - split) * G4A + (n0 + n);
    s[kk][n] = bf ? ldbf((const unsigned short*)src, idx) : ((const float*)src)[idx];
  }
  __syncthreads();
  int lane = tid & 63, tb = tid >> 6;
  unsigned short r[8];
#pragma unroll
  for (int j = 0; j < 8; ++j)
    r[j] = f2bf(s[(lane >> 4) * 8 + j][tb * 16 + (lane & 15)]);
  unsigned short* out = (att ? P.PWatt : P.PWdec) +
      (((long)kblk * 256 + (ng * 4 + tb)) * 64 + lane) * 8;
  *(uint4*)out = *(const uint4*)r;
}

// ---------------- prenet (fused GEMM1+mask1+GEMM2+mask2) -> bf16, reads xT ----------------
__global__ __launch_bounds__(256) void k_prenet(Ptrs P, unsigned k1a, unsigned k1b,
                                                unsigned k2a, unsigned k2b) {
  __shared__ __align__(16) float x_s[32 * 17];
  __shared__ __align__(16) float W_s[16 * 256];
  __shared__ __align__(16) float h1_s[32 * 258];
  int bid = blockIdx.x, tid = threadIdx.x;
  int t = bid >> 1, half = bid & 1;
  int tc = tid & 63, tr = tid >> 6;
  int p0 = tc * 4, bl0 = tr * 8;
  float acc[8][4];
#pragma unroll
  for (int i = 0; i < 8; ++i) { acc[i][0]=0; acc[i][1]=0; acc[i][2]=0; acc[i][3]=0; }

  for (int kc = 0; kc < 32; ++kc) {
    __syncthreads();
    for (int i = tid; i < 32 * 16; i += 256) {
      int bl = i >> 4, kk = i & 15;
      x_s[bl * 17 + kk] = ldbf(P.xT, ((long)t * 64 + half * 32 + bl) * Sn + kc * 16 + kk);
    }
    for (int i = tid; i < 16 * 256; i += 256) {
      int kk = i >> 8, p = i & 255;
      W_s[kk * 256 + p] = P.Wp1[(long)(kc * 16 + kk) * 256 + p];
    }
    __syncthreads();
    for (int kk = 0; kk < 16; ++kk) {
      float4 w = *(const float4*)(W_s + kk * 256 + p0);
#pragma unroll
      for (int i = 0; i < 8; ++i) {
        float x = x_s[(bl0 + i) * 17 + kk];
        acc[i][0] += x * w.x; acc[i][1] += x * w.y; acc[i][2] += x * w.z; acc[i][3] += x * w.w;
      }
    }
  }
#pragma unroll
  for (int i = 0; i < 8; ++i)
#pragma unroll
    for (int j = 0; j < 4; ++j) {
      int bl = bl0 + i, p = p0 + j, bg = half * 32 + bl;
      float v = fmaxf(acc[i][j], 0.f);
      unsigned ft = (unsigned)(((long)t * 64 + bg) * 256 + p);
      v = keepmask(k1a, k1b, ft) ? 2.f * v : 0.f;
      h1_s[bl * 258 + p] = v;
      acc[i][j] = 0.f;
    }
  __syncthreads();
  for (int kc = 0; kc < 16; ++kc) {
    __syncthreads();
    for (int i = tid; i < 16 * 256; i += 256) {
      int kk = i >> 8, p = i & 255;
      W_s[kk * 256 + p] = P.Wp2[(long)(kc * 16 + kk) * 256 + p];
    }
    __syncthreads();
    for (int kk = 0; kk < 16; ++kk) {
      float4 w = *(const float4*)(W_s + kk * 256 + p0);
      int s = kc * 16 + kk;
#pragma unroll
      for (int i = 0; i < 8; ++i) {
        float x = h1_s[(bl0 + i) * 258 + s];
        acc[i][0] += x * w.x; acc[i][1] += x * w.y; acc[i][2] += x * w.z; acc[i][3] += x * w.w;
      }
    }
  }
#pragma unroll
  for (int i = 0; i < 8; ++i)
#pragma unroll
    for (int j = 0; j < 4; ++j) {
      int bg = half * 32 + bl0 + i, p = p0 + j;
      float v = fmaxf(acc[i][j], 0.f);
      unsigned ft = (unsigned)(((long)t * 64 + bg) * 256 + p);
      v = keepmask(k2a, k2b, ft) ? 2.f * v : 0.f;
      P.pre_bf[((long)t * 64 + bg) * 256 + p] = f2bf(v);
    }
}

// ---------------- K1: MFMA gate GEMMs, LDS-staged contiguous A + 4-deep B ring ----------------
// (R10-proven) 512 blocks x 256 thr. XCD-slice mapping:
// bid = (gemm*32 + cg/2)*8 + kc*2 + (cg&1) => bid%8 pins (kc, cg-parity) weight slice.
template<bool ATT>
__device__ __forceinline__ void dev_gemm(const Ptrs& P, int cg, int kc, unsigned short* a_lds) {
  constexpr int CK    = ATT ? ACK : DCK;      // 448 / 640
  constexpr int SUBK  = CK / 2;               // 224 / 320
  constexpr int NKS   = SUBK / 32;            // 7 / 10
  constexpr int PITCH = SUBK + 8;             // <=2-way LDS bank aliasing (free)
  constexpr int GPR   = SUBK / 8;             // 16B groups per row: 28 / 40
  constexpr int KSTR  = ATT ? KATT : KDEC;    // A row stride (contiguous packed)
  int tid = threadIdx.x;
  int lane = tid & 63, w = tid >> 6;
  int nblk = cg * 4 + w;
  const unsigned short* PW = ATT ? P.PWatt : P.PWdec;
  const unsigned short* A  = ATT ? P.attA : P.decA;
  int rlo = lane & 15, khi8 = (lane >> 4) * 8;
  const int k0 = kc * CK;

  f32x4 acc[4];
#pragma unroll
  for (int i = 0; i < 4; ++i) acc[i] = f32x4{0.f, 0.f, 0.f, 0.f};

#pragma unroll
  for (int sub = 0; sub < 2; ++sub) {
    const int kk0 = k0 + sub * SUBK;
    __syncthreads();                            // previous LDS contents consumed
#pragma unroll
    for (int i = 0; i < GPR / 4; ++i) {         // branch-free coalesced staging
      int g = tid + i * 256;
      int row = g / GPR, kg = (g - row * GPR) * 8;
      *(uint4*)(a_lds + row * PITCH + kg) = *(const uint4*)(A + (long)row * KSTR + kk0 + kg);
    }
    __syncthreads();
    const unsigned short* bptr = PW + (((long)(kk0 >> 5) * 256 + nblk) * 64 + lane) * 8;
    s16x8 br[4];
#pragma unroll
    for (int i = 0; i < 4; ++i) br[i] = *(const s16x8*)(bptr + (long)i * 131072);
#pragma unroll
    for (int kb = 0; kb < NKS; ++kb) {
      s16x8 bcur = br[kb & 3];
      if (kb + 4 < NKS) br[kb & 3] = *(const s16x8*)(bptr + (long)(kb + 4) * 131072);
      int abase = kb * 32 + khi8;
#pragma unroll
      for (int mb = 0; mb < 4; ++mb) {
        s16x8 a = *(const s16x8*)(a_lds + (mb * 16 + rlo) * PITCH + abase);
        acc[mb] = __builtin_amdgcn_mfma_f32_16x16x32_bf16(a, bcur, acc[mb], 0, 0, 0);
      }
    }
  }
  float* Pout = (ATT ? P.Patt : P.Pdec) + (long)kc * 64 * G4A;
  int col = nblk * 16 + rlo, rbase = (lane >> 4) * 4;
#pragma unroll
  for (int mb = 0; mb < 4; ++mb)
#pragma unroll
    for (int r = 0; r < 4; ++r)
      Pout[(long)(mb * 16 + rbase + r) * G4A + col] = acc[mb][r];
}

__global__ __launch_bounds__(256) void k_gemm(Ptrs P, int t) {
  __shared__ __align__(16) unsigned short a_lds[64 * 328];  // dec pitch (42 KB)
  int bid = blockIdx.x;
  int low = bid & 7;
  int kc = low >> 1, p = low & 1;
  int rest = bid >> 3;
  bool att = rest < 32;
  int cg = (att ? rest : rest - 32) * 2 + p;
  if (att) { if (t + 1 < Tn) dev_gemm<true>(P, cg, kc, a_lds); }
  else     { if (t >= 0 && t < Tn) dev_gemm<false>(P, cg, kc, a_lds); }
}

// ---------------- K2: pointwise phase (96 blocks x 256) ----------------
// blocks 0..63: att LSTM pw(t)+GMM+alpha+ctx.  blocks 64..95: dec LSTM pw(t-1).
template<typename ST>
__global__ __launch_bounds__(256) void k_point(Ptrs P, int t) {
  __shared__ float ah_s[1024];
  __shared__ float red_s[256];
  __shared__ float tanh_s[128];
  __shared__ float bc_s[2];
  __shared__ float alpha_s[176];
  int bid = blockIdx.x, tid = threadIdx.x;
  if (bid < 64) {
    if (t >= Tn) return;
    int b = bid;
    int bf = *P.flag;
    // copy pre(t+1) into attA pre segment (for next k_gemm)
    if (t + 1 < Tn && tid < 32) {
      *(uint4*)(P.attA + (long)b * KATT + tid * 8) =
          *(const uint4*)(P.pre_bf + ((long)(t + 1) * 64 + b) * Pn + tid * 8);
    }
    int u0 = tid * 4;
    float gv[4][4];
#pragma unroll
    for (int gt = 0; gt < 4; ++gt) {
      float4 a = *(const float4*)(P.bai + gt * 1024 + u0);
      float4 c = *(const float4*)(P.bah + gt * 1024 + u0);
      gv[gt][0] = a.x + c.x; gv[gt][1] = a.y + c.y; gv[gt][2] = a.z + c.z; gv[gt][3] = a.w + c.w;
    }
#pragma unroll
    for (int kc = 0; kc < ACH; ++kc) {
      const float* pa = P.Patt + ((long)kc * 64 + b) * G4A + u0;
#pragma unroll
      for (int gt = 0; gt < 4; ++gt) {
        float4 v = *(const float4*)(pa + gt * 1024);
        gv[gt][0] += v.x; gv[gt][1] += v.y; gv[gt][2] += v.z; gv[gt][3] += v.w;
      }
    }
    float4 oc = *(const float4*)(P.ac + b * 1024 + u0);
    float oldc[4] = {oc.x, oc.y, oc.z, oc.w};
    float hh[4], cc[4];
#pragma unroll
    for (int i = 0; i < 4; ++i) {
      float ii = sigm(gv[0][i]), ff = sigm(gv[1][i]), oo = sigm(gv[3][i]);
      cc[i] = ff * oldc[i] + ii * tanhf(gv[2][i]);
      hh[i] = oo * tanhf(cc[i]);
      ah_s[u0 + i] = hh[i];
    }
    *(float4*)(P.ac + b * 1024 + u0) = make_float4(cc[0], cc[1], cc[2], cc[3]);
    st4bf(P.attA + (long)b * KATT + 768 + u0, hh[0], hh[1], hh[2], hh[3]);
    st4bf(P.decA + (long)b * KDEC + u0,       hh[0], hh[1], hh[2], hh[3]);
    __syncthreads();
    // GMM hidden: tanh(ah @ W_g1 + b_g1)
    {
      int g = tid & 127, hf = tid >> 7;
      const float* wg = P.Wg1 + g;
      float a0 = 0.f, a1 = 0.f;
      int ub = hf * 512;
      for (int u = ub; u < ub + 512; u += 2) {
        a0 += ah_s[u]     * wg[(long)u * 128];
        a1 += ah_s[u + 1] * wg[(long)(u + 1) * 128];
      }
      red_s[tid] = a0 + a1;
    }
    __syncthreads();
    if (tid < 128) tanh_s[tid] = tanhf(red_s[tid] + red_s[tid + 128] + P.bg1[tid]);
    __syncthreads();
    if (tid < 64) {
      float tv0 = tanh_s[tid], tv1 = tanh_s[tid + 64];
      float h0 = tv0 * P.Wg2[2 * tid]     + tv1 * P.Wg2[2 * (tid + 64)];
      float h1 = tv0 * P.Wg2[2 * tid + 1] + tv1 * P.Wg2[2 * (tid + 64) + 1];
#pragma unroll
      for (int o = 32; o; o >>= 1) { h0 += __shfl_down(h0, o); h1 += __shfl_down(h1, o); }
      if (tid == 0) {
        float m  = P.mean[b] + expf(h0) * 8.f;
        float sc = expf(h1) * 8.f;
        P.mean[b] = m;
        long pidx = PARAMS_OFF + ((long)b * Tn + t) * 2;
        store_out(P.out, pidx, h0, bf);
        store_out(P.out, pidx + 1, h1, bf);
        bc_s[0] = m; bc_s[1] = sc;
      }
    }
    __syncthreads();
    float m = bc_s[0], sc = bc_s[1];
    int len = P.mlen[b];
    int ci = (int)floorf(fminf(m, 100000.f));
    int l0 = ci - 80; if (l0 < 0) l0 = 0;
    int l1 = ci + 81; if (l1 > len) l1 = len;
    float inv2 = 0.5f / (sc * sc);
    float invZ = 1.f / (2.50662827463100050242f * sc);
    for (int l = l0 + tid; l < l1; l += 256) {
      float d = (float)l - m;
      float al = expf(-d * d * inv2) * invZ;
      alpha_s[l - l0] = al;
      store_out(P.out, ALIGNS_OFF + ((long)b * Tn + t) * Ln + l, al, bf);
    }
    __syncthreads();
    int nl = l1 - l0;
    ST* ctx_all = (ST*)P.ctx_all;
    int e0 = tid * 2;
    float s0 = 0.f, s1 = 0.f;
    if (bf) {
      const unsigned* mem = (const unsigned*)((const unsigned short*)P.mem +
                                              ((long)b * Ln + l0) * En + e0);
      for (int l = 0; l < nl; ++l) {
        float al = alpha_s[l];
        unsigned q = mem[(long)l * (En / 2)];
        s0 += al * bflo(q);
        s1 += al * bfhi(q);
      }
    } else {
      const float* mem = (const float*)P.mem + ((long)b * Ln + l0) * En + e0;
      for (int l = 0; l < nl; ++l) {
        float al = alpha_s[l];
        float2 v = *(const float2*)(mem + (long)l * En);
        s0 += al * v.x;
        s1 += al * v.y;
      }
    }
    unsigned q = (unsigned)f2bf(s0) | ((unsigned)f2bf(s1) << 16);
    *(unsigned*)(P.attA + (long)b * KATT + 256 + e0) = q;
    *(unsigned*)(P.decA + (long)b * KDEC + 1024 + e0) = q;
    st_store(ctx_all, ((long)t * 64 + b) * En + e0, s0);
    st_store(ctx_all, ((long)t * 64 + b) * En + e0 + 1, s1);
  } else {
    if (t == 0) return;
    int bb = bid - 64;
    int b = bb * 2 + (tid >> 7);
    int u0 = (tid & 127) * 8;
    ST* dh_all = (ST*)P.dh_all;
    float gv[4][8];
#pragma unroll
    for (int gt = 0; gt < 4; ++gt) {
      float4 a0 = *(const float4*)(P.bdi + gt * 1024 + u0);
      float4 a1 = *(const float4*)(P.bdi + gt * 1024 + u0 + 4);
      float4 c0 = *(const float4*)(P.bdh + gt * 1024 + u0);
      float4 c1 = *(const float4*)(P.bdh + gt * 1024 + u0 + 4);
      gv[gt][0] = a0.x + c0.x; gv[gt][1] = a0.y + c0.y; gv[gt][2] = a0.z + c0.z; gv[gt][3] = a0.w + c0.w;
      gv[gt][4] = a1.x + c1.x; gv[gt][5] = a1.y + c1.y; gv[gt][6] = a1.z + c1.z; gv[gt][7] = a1.w + c1.w;
    }
#pragma unroll
    for (int kc = 0; kc < DCH; ++kc) {
      const float* pd = P.Pdec + ((long)kc * 64 + b) * G4A + u0;
#pragma unroll
      for (int gt = 0; gt < 4; ++gt) {
        float4 v0 = *(const float4*)(pd + gt * 1024);
        float4 v1 = *(const float4*)(pd + gt * 1024 + 4);
        gv[gt][0] += v0.x; gv[gt][1] += v0.y; gv[gt][2] += v0.z; gv[gt][3] += v0.w;
        gv[gt][4] += v1.x; gv[gt][5] += v1.y; gv[gt][6] += v1.z; gv[gt][7] += v1.w;
      }
    }
    float4 oc0 = *(const float4*)(P.dc + b * 1024 + u0);
    float4 oc1 = *(const float4*)(P.dc + b * 1024 + u0 + 4);
    float oldc[8] = {oc0.x, oc0.y, oc0.z, oc0.w, oc1.x, oc1.y, oc1.z, oc1.w};
    float hh[8], cc[8];
#pragma unroll
    for (int i = 0; i < 8; ++i) {
      float ii = sigm(gv[0][i]), ff = sigm(gv[1][i]), oo = sigm(gv[3][i]);
      cc[i] = ff * oldc[i] + ii * tanhf(gv[2][i]);
      hh[i] = oo * tanhf(cc[i]);
    }
    *(float4*)(P.dc + b * 1024 + u0)     = make_float4(cc[0], cc[1], cc[2], cc[3]);
    *(float4*)(P.dc + b * 1024 + u0 + 4) = make_float4(cc[4], cc[5], cc[6], cc[7]);
    st8bf(P.decA + (long)b * KDEC + 1536 + u0, hh);
#pragma unroll
    for (int i = 0; i < 8; ++i)
      st_store(dh_all, ((long)(t - 1) * 64 + b) * 1024 + u0 + i, hh[i]);
  }
}

// ---------------- final projection: logits = [dh, ctx] @ W_proj + b ----------------
template<typename ST>
__global__ __launch_bounds__(256) void k_proj(Ptrs P) {
  __shared__ __align__(16) float A_s[64][65];
  __shared__ __align__(16) float W_s[64 * 160];
  int t = blockIdx.x, tid = threadIdx.x;
  int bf = *P.flag;
  const ST* dh_all = (const ST*)P.dh_all;
  const ST* ctx_all = (const ST*)P.ctx_all;
  int tc = tid & 15, tr = tid >> 4;
  int c0 = tc * 10, b0 = tr * 4;
  float acc[4][10];
#pragma unroll
  for (int i = 0; i < 4; ++i)
#pragma unroll
    for (int j = 0; j < 10; ++j) acc[i][j] = 0.f;
  for (int k0 = 0; k0 < KPROJ; k0 += 64) {
    __syncthreads();
    for (int i = tid; i < 64 * 64; i += 256) {
      int b = i >> 6, kk = i & 63;
      int k = k0 + kk;
      float v = (k < Dn) ? st_load(dh_all, ((long)t * 64 + b) * Dn + k)
                         : st_load(ctx_all, ((long)t * 64 + b) * En + (k - Dn));
      A_s[b][kk] = v;
    }
    for (int i = tid; i < 64 * 160; i += 256) {
      int kk = i / 160, c = i - kk * 160;
      W_s[kk * 160 + c] = (c < Vn) ? P.Wpr[(long)(k0 + kk) * Vn + c] : 0.f;
    }
    __syncthreads();
    for (int kk = 0; kk < 64; ++kk) {
      float xs[4];
#pragma unroll
      for (int i = 0; i < 4; ++i) xs[i] = A_s[b0 + i][kk];
#pragma unroll
      for (int j = 0; j < 10; ++j) {
        float w = W_s[kk * 160 + c0 + j];
#pragma unroll
        for (int i = 0; i < 4; ++i) acc[i][j] += xs[i] * w;
      }
    }
  }
#pragma unroll
  for (int i = 0; i < 4; ++i)
#pragma unroll
    for (int j = 0; j < 10; ++j) {
      int c = c0 + j;
      if (c < Vn) {
        int b = b0 + i;
        store_out(P.out, LOGITS_OFF + ((long)b * Tn + t) * Vn + c, acc[i][j] + P.bpr[c], bf);
      }
    }
}

// ---------------- host ----------------
template<typename ST>
static void run_pipeline(const Ptrs& P, hipStream_t stream) {
  k_xpose<<<1024, 256, 0, stream>>>(P);
  k_prenet<<<Tn * 2, 256, 0, stream>>>(P, DK1.a, DK1.b, DK2.a, DK2.b);
  k_precopy<<<1, 256, 0, stream>>>(P);                 // pre(0) -> attA
  k_gemm<<<512, 256, 0, stream>>>(P, -1);              // prologue: att gates for t=0
  for (int t = 0; t <= Tn; ++t) {
    k_point<ST><<<96, 256, 0, stream>>>(P, t);         // att pw(t)+GMM+ctx | dec pw(t-1)
    if (t < Tn) k_gemm<<<512, 256, 0, stream>>>(P, t); // att gates(t+1) + dec gates(t)
  }
  k_proj<ST><<<Tn, 256, 0, stream>>>(P);
}

extern "C" void kernel_launch(void* const* d_in, const int* in_sizes, int n_in,
                              void* d_out, int out_size, void* d_ws, size_t ws_size,
                              hipStream_t stream) {
  (void)in_sizes; (void)n_in; (void)out_size;
  char* base = (char*)d_ws;
  int* flag = (int*)base;
  size_t off = 256;
  auto allocf = [&](size_t n) -> float* {
    float* p = (float*)(base + off);
    off += ((n * 4 + 255) / 256) * 256;
    return p;
  };
  auto allocu = [&](size_t n) -> unsigned short* {
    unsigned short* p = (unsigned short*)(base + off);
    off += ((n * 2 + 255) / 256) * 256;
    return p;
  };
  float* Wp1 = allocf(131072);
  float* Wp2 = allocf(65536);
  float* bai = allocf(4096);
  float* bah = allocf(4096);
  float* Wg1 = allocf(131072);
  float* bg1 = allocf(128);
  float* Wg2 = allocf(256);
  float* bdi = allocf(4096);
  float* bdh = allocf(4096);
  float* Wpr = allocf(227328);
  float* bpr = allocf(148);
  unsigned short* PWatt = allocu((size_t)NKB_ATT * 256 * 512);  // bf16 packed weights
  unsigned short* PWdec = allocu((size_t)NKB_DEC * 256 * 512);
  unsigned short* pre_bf = allocu((size_t)Tn * 64 * Pn);
  unsigned short* xT = allocu((size_t)Tn * 64 * Sn);            // transposed prenet input
  float* Patt = allocf((size_t)ACH * 64 * G4A);
  float* Pdec = allocf((size_t)DCH * 64 * G4A);
  // zero region: ac, dc, mean (f32) then attA, decA (bf16), all contiguous 256B-mult
  float* ac = allocf(65536);
  float* dc = allocf(65536);
  float* mean = allocf(64);
  unsigned short* attA = allocu((size_t)64 * KATT);   // 114688 elems
  unsigned short* decA = allocu((size_t)64 * KDEC);   // 163840 elems
  size_t fixed = off;
  size_t nDH = (size_t)Tn * 64 * Dn, nCX = (size_t)Tn * 64 * En;
  bool f32tier = (fixed + (nDH + nCX) * 4 <= ws_size);
  bool b16tier = (fixed + (nDH + nCX) * 2 <= ws_size);
  if (!f32tier && !b16tier) return;

  Ptrs P;
  P.Wp1=Wp1; P.Wp2=Wp2; P.bai=bai; P.bah=bah; P.Wg1=Wg1; P.bg1=bg1; P.Wg2=Wg2;
  P.bdi=bdi; P.bdh=bdh; P.Wpr=Wpr; P.bpr=bpr;
  P.PWatt=PWatt; P.PWdec=PWdec; P.pre_bf=pre_bf; P.attA=attA; P.decA=decA; P.xT=xT;
  P.Patt=Patt; P.Pdec=Pdec; P.ac=ac; P.dc=dc; P.mean=mean;
  size_t esz = f32tier ? 4 : 2;
  P.dh_all  = base + fixed;
  P.ctx_all = base + fixed + nDH * esz;
  P.mem = d_in[0]; P.din = d_in[1]; P.mlen = (const int*)d_in[2];
  P.w_ai = d_in[5]; P.w_ah = d_in[6]; P.w_di = d_in[12]; P.w_dh = d_in[13];
  P.flag = flag; P.out = d_out;

  k_detect<<<1, 256, 0, stream>>>(d_in[0], flag);

  struct CV { const void* s; float* d; long n; };
  const CV cv[11] = {
    {d_in[3], Wp1, 131072}, {d_in[4], Wp2, 65536},
    {d_in[7], bai, 4096}, {d_in[8], bah, 4096},
    {d_in[9], Wg1, 131072}, {d_in[10], bg1, 128}, {d_in[11], Wg2, 256},
    {d_in[14], bdi, 4096}, {d_in[15], bdh, 4096},
    {d_in[16], Wpr, 227328}, {d_in[17], bpr, 148},
  };
  for (int i = 0; i < 11; ++i) {
    long g = (cv[i].n + 255) / 256; if (g > 1024) g = 1024;
    k_convert<<<(int)g, 256, 0, stream>>>(cv[i].s, cv[i].d, cv[i].n, flag);
  }
  k_pack<<<(NKB_ATT + NKB_DEC) * 64, 256, 0, stream>>>(P);
  // zero: ac+dc+mean = 131136 f32; attA 114688 u16 = 57344 words; decA 163840 u16 = 81920 words
  k_zero_f32<<<512, 256, 0, stream>>>(ac, 131136 + 57344 + 81920);
  k_zero_aligns<<<2048, 256, 0, stream>>>(d_out, flag);

  if (f32tier) run_pipeline<float>(P, stream);
  else         run_pipeline<unsigned short>(P, stream);
}